// Round 10
// baseline (1301.082 us; speedup 1.0000x reference)
//
#include <hip/hip_runtime.h>

// GPT2-like forward, MI355X. Round 10:
// - head GEMM: reverted to R8's proven 8-phase schedule (R9's 4-phase regressed)
// - attention: barrier-FREE — K/V MFMA fragments loaded directly from global
//   (L2-resident, 16 blocks/head reuse); only per-wave Pw stays in LDS
// - everything else unchanged from R8

#define T_SEQ 1024
#define NTOK  2048   // B*T
#define DM    1024
#define DFF   4096
#define NH    16
#define DH    64
#define NL    6
#define VOCAB 32000

typedef short sx8 __attribute__((ext_vector_type(8)));          // 8 bf16 (4 VGPR) MFMA frag
typedef float fx4 __attribute__((ext_vector_type(4)));          // MFMA acc
typedef unsigned short usx4 __attribute__((ext_vector_type(4)));
typedef unsigned int   uix4 __attribute__((ext_vector_type(4))); // 16B copy

__device__ __forceinline__ unsigned short f2bf(float f) {
  union { float f; unsigned u; } c; c.f = f;
  unsigned r = c.u + 0x7FFFu + ((c.u >> 16) & 1u);   // round-nearest-even
  return (unsigned short)(r >> 16);
}
__device__ __forceinline__ float bf2f(unsigned short u) {
  union { unsigned u; float f; } c; c.u = ((unsigned)u) << 16;
  return c.f;
}
// HW packed f32->2xbf16 convert (no builtin on gfx950; T12 primitive)
__device__ __forceinline__ unsigned cvt_pk_bf16(float lo, float hi) {
  unsigned r;
  asm("v_cvt_pk_bf16_f32 %0, %1, %2" : "=v"(r) : "v"(lo), "v"(hi));
  return r;
}

__device__ __forceinline__ void gload_lds16(const unsigned short* g, unsigned short* l) {
  __builtin_amdgcn_global_load_lds(
      (const __attribute__((address_space(1))) unsigned int*)g,
      (__attribute__((address_space(3))) unsigned int*)l, 16, 0, 0);
}

// bijective XCD-chunked swizzle (m204)
__device__ __forceinline__ int xcd_swizzle(int orig, int nwg) {
  int q = nwg >> 3, r = nwg & 7;
  int xcd = orig & 7, idx = orig >> 3;
  int base = (xcd < r) ? xcd * (q + 1) : r * (q + 1) + (xcd - r) * q;
  return base + idx;
}

// ---------------- fused embedding + ln1(layer0) ----------------
__global__ __launch_bounds__(256) void k_embed_ln(const int* __restrict__ idx,
                                                  const float* __restrict__ tok,
                                                  const float* __restrict__ pos,
                                                  const float* __restrict__ g,
                                                  const float* __restrict__ b,
                                                  float* __restrict__ x,
                                                  unsigned short* __restrict__ h) {
  int token = blockIdx.x;
  int t = token & (T_SEQ - 1);
  int id = idx[token];
  int tid = threadIdx.x;
  int c = tid * 4;
  float4 tv = *(const float4*)&tok[(size_t)id * DM + c];
  float4 pv = *(const float4*)&pos[(size_t)t * DM + c];
  float4 v;
  v.x = tv.x + pv.x; v.y = tv.y + pv.y; v.z = tv.z + pv.z; v.w = tv.w + pv.w;
  *(float4*)&x[(size_t)token * DM + c] = v;
  float s = v.x + v.y + v.z + v.w;
  float q = v.x * v.x + v.y * v.y + v.z * v.z + v.w * v.w;
  for (int off = 32; off > 0; off >>= 1) {
    s += __shfl_down(s, off);
    q += __shfl_down(q, off);
  }
  __shared__ float red[8];
  int wid = tid >> 6, lane = tid & 63;
  if (lane == 0) { red[wid] = s; red[4 + wid] = q; }
  __syncthreads();
  s = red[0] + red[1] + red[2] + red[3];
  q = red[4] + red[5] + red[6] + red[7];
  float mu = s * (1.0f / DM);
  float var = q * (1.0f / DM) - mu * mu;
  float rstd = rsqrtf(var + 1e-5f);
  float4 gg = *(const float4*)&g[c];
  float4 bb = *(const float4*)&b[c];
  uint2 o;
  o.x = cvt_pk_bf16((v.x - mu) * rstd * gg.x + bb.x, (v.y - mu) * rstd * gg.y + bb.y);
  o.y = cvt_pk_bf16((v.z - mu) * rstd * gg.z + bb.z, (v.w - mu) * rstd * gg.w + bb.w);
  *(uint2*)&h[(size_t)token * DM + c] = o;
}

// ------------- fused split-K(4) reduce (bf16 partials) + residual + layernorm -------------
__global__ __launch_bounds__(256) void k_reduce_ln(const unsigned short* __restrict__ part,
                                                   float* __restrict__ x,
                                                   const float* __restrict__ g,
                                                   const float* __restrict__ b,
                                                   unsigned short* __restrict__ h) {
  int row = blockIdx.x;
  int tid = threadIdx.x;
  int c = tid * 4;
  float4 v = *(const float4*)&x[(size_t)row * DM + c];
#pragma unroll
  for (int s4 = 0; s4 < 4; ++s4) {
    usx4 p = *(const usx4*)&part[((size_t)s4 * NTOK + row) * DM + c];
    v.x += bf2f(p[0]); v.y += bf2f(p[1]); v.z += bf2f(p[2]); v.w += bf2f(p[3]);
  }
  *(float4*)&x[(size_t)row * DM + c] = v;
  float s = v.x + v.y + v.z + v.w;
  float q = v.x * v.x + v.y * v.y + v.z * v.z + v.w * v.w;
  for (int off = 32; off > 0; off >>= 1) {
    s += __shfl_down(s, off);
    q += __shfl_down(q, off);
  }
  __shared__ float red[8];
  int wid = tid >> 6, lane = tid & 63;
  if (lane == 0) { red[wid] = s; red[4 + wid] = q; }
  __syncthreads();
  s = red[0] + red[1] + red[2] + red[3];
  q = red[4] + red[5] + red[6] + red[7];
  float mu = s * (1.0f / DM);
  float var = q * (1.0f / DM) - mu * mu;
  float rstd = rsqrtf(var + 1e-5f);
  float4 gg = *(const float4*)&g[c];
  float4 bb = *(const float4*)&b[c];
  uint2 o;
  o.x = cvt_pk_bf16((v.x - mu) * rstd * gg.x + bb.x, (v.y - mu) * rstd * gg.y + bb.y);
  o.y = cvt_pk_bf16((v.z - mu) * rstd * gg.z + bb.z, (v.w - mu) * rstd * gg.w + bb.w);
  *(uint2*)&h[(size_t)row * DM + c] = o;
}

// ---------------- weight convert+transpose core ----------------
__device__ __forceinline__ void wtrans_body(const float* __restrict__ W,
                                            unsigned short* __restrict__ WT,
                                            int K, int N, int k0, int n0, int tid) {
  __shared__ float t[64][68];
#pragma unroll
  for (int i = 0; i < 4; ++i) {
    int chunk = i * 256 + tid;
    int r = chunk >> 4, c = (chunk & 15) << 2;
    float4 v = *(const float4*)&W[(size_t)(k0 + r) * N + n0 + c];
    t[r][c] = v.x; t[r][c + 1] = v.y; t[r][c + 2] = v.z; t[r][c + 3] = v.w;
  }
  __syncthreads();
#pragma unroll
  for (int i = 0; i < 4; ++i) {
    int chunk = i * 256 + tid;
    int n = chunk >> 4, c = (chunk & 15) << 2;
    uint2 o;
    o.x = cvt_pk_bf16(t[c][n], t[c + 1][n]);
    o.y = cvt_pk_bf16(t[c + 2][n], t[c + 3][n]);
    *(uint2*)&WT[(size_t)(n0 + n) * K + k0 + c] = o;
  }
}

// standalone (head)
__global__ __launch_bounds__(256) void k_wtrans(const float* __restrict__ W,
                                                unsigned short* __restrict__ WT,
                                                int K, int N) {
  wtrans_body(W, WT, K, N, blockIdx.x * 64, blockIdx.y * 64, threadIdx.x);
}

// all 4 per-layer weights in one launch (segmented block ranges)
__global__ __launch_bounds__(256) void k_wtrans4(const float* __restrict__ W0,
                                                 const float* __restrict__ W1,
                                                 const float* __restrict__ W2,
                                                 const float* __restrict__ W3,
                                                 unsigned short* __restrict__ T0,
                                                 unsigned short* __restrict__ T1,
                                                 unsigned short* __restrict__ T2,
                                                 unsigned short* __restrict__ T3) {
  int id = blockIdx.x;
  const float* W; unsigned short* WT; int K, N, lid;
  if (id < 768)       { W = W0; WT = T0; K = 1024; N = 3072; lid = id; }
  else if (id < 1024) { W = W1; WT = T1; K = 1024; N = 1024; lid = id - 768; }
  else if (id < 2048) { W = W2; WT = T2; K = 1024; N = 4096; lid = id - 1024; }
  else                { W = W3; WT = T3; K = 4096; N = 1024; lid = id - 2048; }
  int kb = K >> 6;
  wtrans_body(W, WT, K, N, (lid % kb) * 64, (lid / kb) * 64, threadIdx.x);
}

// ---------------- 128x128 GEMM, T3 2-phase prefetch ----------------
// EPI: 0=qkv scatter(+bias, V transposed), 1=gelu(+bias)->bf16, 2=+bias -> bf16 partials
template <int EPI>
__global__ __launch_bounds__(256) void k_gemm(const unsigned short* __restrict__ A,
                                              const unsigned short* __restrict__ BT,
                                              const float* __restrict__ bias,
                                              unsigned short* __restrict__ part,
                                              unsigned short* __restrict__ outb,
                                              float* __restrict__ outf,
                                              int N, int K, int NT, int KS) {
  __shared__ unsigned short As[2][128 * 64];
  __shared__ unsigned short Bs[2][128 * 64];
  int tid = threadIdx.x;
  int wid = tid >> 6, lane = tid & 63;
  int lr = lane & 15, lg = lane >> 4;

  int id = xcd_swizzle(blockIdx.x, gridDim.x);
  int mt = id & 15;
  int rest = id >> 4;
  int nt = rest % NT;
  int ks = rest / NT;
  int m0 = mt * 128, n0 = nt * 128;
  int Kslice = K / KS;
  int kbeg = ks * Kslice;
  int nk = Kslice >> 6;

  int wm = (wid >> 1) * 64, wn = (wid & 1) * 64;

  fx4 acc[4][4] = {};

#define GSTAGE(buf, kt)                                                         \
  {                                                                             \
    _Pragma("unroll")                                                           \
    for (int i = 0; i < 4; ++i) {                                               \
      int chunk = i * 256 + tid;                                                \
      int r = chunk >> 3, slot = chunk & 7;                                     \
      int c = ((slot ^ (r & 7)) << 3);                                          \
      gload_lds16(&A[(size_t)(m0 + r) * K + (kt) + c], &As[buf][chunk << 3]);   \
      gload_lds16(&BT[(size_t)(n0 + r) * K + (kt) + c], &Bs[buf][chunk << 3]);  \
    }                                                                           \
  }

  GSTAGE(0, kbeg);
  for (int ik = 0; ik < nk; ++ik) {
    int cur = ik & 1;
    if (ik + 1 < nk) {
      GSTAGE(cur ^ 1, kbeg + (ik + 1) * 64);
      asm volatile("s_waitcnt vmcnt(8)" ::: "memory");   // oldest 8 = current tile
    } else {
      asm volatile("s_waitcnt vmcnt(0)" ::: "memory");
    }
    __builtin_amdgcn_sched_barrier(0);
    __builtin_amdgcn_s_barrier();                        // current tile visible to all
    __builtin_amdgcn_sched_barrier(0);
#pragma unroll
    for (int kk = 0; kk < 2; ++kk) {
      int slotz = (kk * 4 + lg) ^ (lr & 7);
      sx8 fa[4], fb[4];
#pragma unroll
      for (int mi = 0; mi < 4; ++mi)
        fa[mi] = *(const sx8*)&As[cur][(wm + mi * 16 + lr) * 64 + slotz * 8];
#pragma unroll
      for (int ni = 0; ni < 4; ++ni)
        fb[ni] = *(const sx8*)&Bs[cur][(wn + ni * 16 + lr) * 64 + slotz * 8];
#pragma unroll
      for (int mi = 0; mi < 4; ++mi)
#pragma unroll
        for (int ni = 0; ni < 4; ++ni)
          acc[mi][ni] = __builtin_amdgcn_mfma_f32_16x16x32_bf16(fb[ni], fa[mi], acc[mi][ni], 0, 0, 0);
    }
    asm volatile("s_waitcnt lgkmcnt(0)" ::: "memory");   // my ds_reads landed
    __builtin_amdgcn_sched_barrier(0);
    __builtin_amdgcn_s_barrier();                        // safe to overwrite cur next iter
  }
#undef GSTAGE

#pragma unroll
  for (int ni = 0; ni < 4; ++ni) {
    int col0 = n0 + wn + ni * 16 + lg * 4;
    float4 bv = {0.f, 0.f, 0.f, 0.f};
    if (bias && ks == 0) bv = *(const float4*)&bias[col0];
#pragma unroll
    for (int mi = 0; mi < 4; ++mi) {
      int row = m0 + wm + mi * 16 + lr;
      float v0 = acc[mi][ni][0] + bv.x;
      float v1 = acc[mi][ni][1] + bv.y;
      float v2 = acc[mi][ni][2] + bv.z;
      float v3 = acc[mi][ni][3] + bv.w;
      if constexpr (EPI == 0) {
        int bb = row >> 10, tt = row & 1023;
        if (col0 < 2048) {
          int which = col0 >> 10;
          int hc = col0 & 1023;
          uint2 o = {cvt_pk_bf16(v0, v1), cvt_pk_bf16(v2, v3)};
          *(uint2*)&outb[(size_t)which * NTOK * DM +
                         (((size_t)bb * NH + (hc >> 6)) * T_SEQ + tt) * DH + (hc & 63)] = o;
        } else {
          int dc = col0 - 2048;
          unsigned short* vt = outb + (size_t)2 * NTOK * DM;
          size_t base = (((size_t)bb * NH + (dc >> 6)) * DH + (dc & 63)) * T_SEQ + tt;
          vt[base] = f2bf(v0);
          vt[base + T_SEQ] = f2bf(v1);
          vt[base + 2 * T_SEQ] = f2bf(v2);
          vt[base + 3 * T_SEQ] = f2bf(v3);
        }
      } else if constexpr (EPI == 1) {
        float g0 = 0.5f * v0 * (1.0f + erff(v0 * 0.70710678f));
        float g1 = 0.5f * v1 * (1.0f + erff(v1 * 0.70710678f));
        float g2 = 0.5f * v2 * (1.0f + erff(v2 * 0.70710678f));
        float g3 = 0.5f * v3 * (1.0f + erff(v3 * 0.70710678f));
        uint2 o = {cvt_pk_bf16(g0, g1), cvt_pk_bf16(g2, g3)};
        *(uint2*)&outb[(size_t)row * N + col0] = o;
      } else {  // bf16 partial slice (split-K)
        uint2 o = {cvt_pk_bf16(v0, v1), cvt_pk_bf16(v2, v3)};
        *(uint2*)&part[((size_t)ks * NTOK + row) * DM + col0] = o;
      }
    }
  }
}

// ---------------- 256x256 8-phase GEMM (head) — R8 proven version ----------------
#define LDSUB(buf, ab, kk) (lds + (((buf) * 2 + (ab)) * 2 + (kk)) * 8192)

__device__ __forceinline__ void stage_half(const unsigned short* g, int rowstride,
                                           unsigned short* ldsbase, int tid, int k0) {
#pragma unroll
  for (int r = 0; r < 2; ++r) {
    int chunk = r * 512 + tid;
    int row = chunk >> 2, slot = chunk & 3;
    gload_lds16(g + (size_t)row * rowstride + k0 + ((slot ^ ((row >> 1) & 3)) << 3),
                ldsbase + (chunk << 3));
  }
}

__global__ __launch_bounds__(512, 2) void k_gemm256(const unsigned short* __restrict__ A,
                                                    const unsigned short* __restrict__ BT,
                                                    float* __restrict__ outf,
                                                    int N, int K) {
  __shared__ unsigned short lds[8 * 8192];   // 128 KB
  int tid = threadIdx.x;
  int wid = tid >> 6, lane = tid & 63;
  int lr = lane & 15, lg = lane >> 4;
  int wm2 = wid >> 2, wn4 = wid & 3;
  int id = xcd_swizzle(blockIdx.x, gridDim.x);
  int mt = id & 7, nt = id >> 3;          // mt fastest: 8 blocks share B panel
  int m0 = mt * 256, n0 = nt * 256;
  const unsigned short* Ab = A + (size_t)m0 * K;
  const unsigned short* Bb = BT + (size_t)n0 * K;
  int NIT = K >> 7;                        // 2 K-tiles (of 64) per iteration
  int swz = (lg ^ ((lr >> 1) & 3)) << 3;   // matches stage_half swizzle
  float* obase = outf + (size_t)(m0 + wm2 * 128 + lr) * N + n0 + wn4 * 64 + lg * 4;

  fx4 acc[8][4] = {};

  // prologue: tile0 {A0,B0,A1,B1}, tile1 {A0,B0,A1} = 7 half-tiles (14 loads)
  stage_half(Ab, K, LDSUB(0, 0, 0), tid, 0);
  stage_half(Bb, K, LDSUB(0, 1, 0), tid, 0);
  stage_half(Ab, K, LDSUB(0, 0, 1), tid, 32);
  stage_half(Bb, K, LDSUB(0, 1, 1), tid, 32);
  stage_half(Ab, K, LDSUB(1, 0, 0), tid, 64);
  stage_half(Bb, K, LDSUB(1, 1, 0), tid, 64);
  stage_half(Ab, K, LDSUB(1, 0, 1), tid, 96);
  asm volatile("s_waitcnt vmcnt(6)" ::: "memory");   // tile0 fully staged
  __builtin_amdgcn_s_barrier();

#define PHASE(BUF, KK, NHH, LOADA, STG, VMW)                                         \
  {                                                                                  \
    if (LOADA) {                                                                     \
      const unsigned short* sA = LDSUB(BUF, 0, KK);                                  \
      _Pragma("unroll")                                                              \
      for (int mi = 0; mi < 8; ++mi)                                                 \
        fa[mi] = *(const sx8*)&sA[(wm2 * 128 + mi * 16 + lr) * 32 + swz];            \
    }                                                                                \
    {                                                                                \
      const unsigned short* sB = LDSUB(BUF, 1, KK);                                  \
      _Pragma("unroll")                                                              \
      for (int j = 0; j < 2; ++j)                                                    \
        fb[j] = *(const sx8*)&sB[(wn4 * 64 + (NHH) * 32 + j * 16 + lr) * 32 + swz];  \
    }                                                                                \
    STG;                                                                             \
    VMW;                                                                             \
    __builtin_amdgcn_sched_barrier(0);                                               \
    __builtin_amdgcn_s_barrier();                                                    \
    asm volatile("s_waitcnt lgkmcnt(0)" ::: "memory");                               \
    __builtin_amdgcn_sched_barrier(0);                                               \
    __builtin_amdgcn_s_setprio(1);                                                   \
    _Pragma("unroll")                                                                \
    for (int mi = 0; mi < 8; ++mi) {                                                 \
      acc[mi][(NHH) * 2 + 0] = __builtin_amdgcn_mfma_f32_16x16x32_bf16(              \
          fb[0], fa[mi], acc[mi][(NHH) * 2 + 0], 0, 0, 0);                           \
      acc[mi][(NHH) * 2 + 1] = __builtin_amdgcn_mfma_f32_16x16x32_bf16(              \
          fb[1], fa[mi], acc[mi][(NHH) * 2 + 1], 0, 0, 0);                           \
    }                                                                                \
    __builtin_amdgcn_s_setprio(0);                                                   \
    __builtin_amdgcn_sched_barrier(0);                                               \
    __builtin_amdgcn_s_barrier();                                                    \
  }

  for (int it = 0; it < NIT; ++it) {
    bool st = (it < NIT - 1);
    bool last = (it == NIT - 1);
    int t1k = (2 * it + 1) * 64;
    int t2k = (2 * it + 2) * 64;
    int t3k = (2 * it + 3) * 64;
    sx8 fa[8], fb[2];

    PHASE(0, 0, 0, true,
          { stage_half(Bb, K, LDSUB(1, 1, 1), tid, t1k + 32); }, {});
    PHASE(0, 0, 1, false,
          { if (st) stage_half(Ab, K, LDSUB(0, 0, 0), tid, t2k); }, {});
    PHASE(0, 1, 0, true,
          { if (st) stage_half(Bb, K, LDSUB(0, 1, 0), tid, t2k); }, {});
    PHASE(0, 1, 1, false,
          { if (st) stage_half(Ab, K, LDSUB(0, 0, 1), tid, t2k + 32); },
          { if (last) { asm volatile("s_waitcnt vmcnt(0)" ::: "memory"); }
            else      { asm volatile("s_waitcnt vmcnt(6)" ::: "memory"); } });
    PHASE(1, 0, 0, true,
          { if (st) stage_half(Bb, K, LDSUB(0, 1, 1), tid, t2k + 32); }, {});
    PHASE(1, 0, 1, false,
          { if (st) stage_half(Ab, K, LDSUB(1, 0, 0), tid, t3k); }, {});
    PHASE(1, 1, 0, true,
          { if (st) stage_half(Bb, K, LDSUB(1, 1, 0), tid, t3k); }, {});
    // split epilogue: nj 0,1 final after p7 -> store overlapped with p8
    if (last) {
#pragma unroll
      for (int mi = 0; mi < 8; ++mi) {
        *(float4*)(obase + (size_t)mi * 16 * N) =
            (float4){acc[mi][0][0], acc[mi][0][1], acc[mi][0][2], acc[mi][0][3]};
        *(float4*)(obase + (size_t)mi * 16 * N + 16) =
            (float4){acc[mi][1][0], acc[mi][1][1], acc[mi][1][2], acc[mi][1][3]};
      }
    }
    PHASE(1, 1, 1, false,
          { if (st) stage_half(Ab, K, LDSUB(1, 0, 1), tid, t3k + 32); },
          { if (!last) { asm volatile("s_waitcnt vmcnt(6)" ::: "memory"); } });
  }
#undef PHASE

  // remaining quadrants nj 2,3
#pragma unroll
  for (int mi = 0; mi < 8; ++mi) {
    *(float4*)(obase + (size_t)mi * 16 * N + 32) =
        (float4){acc[mi][2][0], acc[mi][2][1], acc[mi][2][2], acc[mi][2][3]};
    *(float4*)(obase + (size_t)mi * 16 * N + 48) =
        (float4){acc[mi][3][0], acc[mi][3][1], acc[mi][3][2], acc[mi][3][3]};
  }
}

// ---------------- flash attention: barrier-free, direct-from-global fragments ----------------
// grid 512: id -> bh = id>>4, qt = 15-(id&15). 4 independent waves (wave w: q rows
// qt*64+w*16..+15). K-frag kb = gk[(t0+mi*16+lr)*64 + kk*32+lg*8] (16B/lane, L2-hot);
// V^T-frag vb = gvt[(dt*16+lr)*T + kt0+kk*32+lg*8]. No __syncthreads anywhere; Pw is
// per-wave (write->read ordered by lgkmcnt within the wave).
__global__ __launch_bounds__(256) void k_attn(const unsigned short* __restrict__ gq,
                                              const unsigned short* __restrict__ gk,
                                              const unsigned short* __restrict__ gvt,
                                              unsigned short* __restrict__ y) {
  __shared__ unsigned short Pw[4][16 * 136];
  int id = xcd_swizzle(blockIdx.x, gridDim.x);
  int bh = id >> 4, qt = 15 - (id & 15);
  int tid = threadIdx.x, wid = tid >> 6, lane = tid & 63;
  int lr = lane & 15, lg = lane >> 4;
  int q0 = qt * 64 + wid * 16;
  int qg = q0 + lr;
  const float SCL = 0.125f * 1.44269504f;   // 1/sqrt(64) * log2(e)

  const unsigned short* kbase = gk + (size_t)bh * T_SEQ * DH + lg * 8;
  const unsigned short* vtbase = gvt + (size_t)bh * DH * T_SEQ + lg * 8;

  sx8 qf[2];
  {
    const unsigned short* qp = gq + ((size_t)bh * T_SEQ + qg) * DH + lg * 8;
    qf[0] = *(const sx8*)qp;
    qf[1] = *(const sx8*)(qp + 32);
  }

  fx4 yacc[4] = {};
  float mrun = -1e30f, lrun = 0.f;   // lane-local (q-row = lr), log2 domain

  int jmax = qt >> 1;
  for (int j = 0; j <= jmax; ++j) {
    int kt0 = j * 128;

    // S^T = K Q^T : A-frags straight from global (L2-hot)
    fx4 st[8] = {};
#pragma unroll
    for (int kk = 0; kk < 2; ++kk) {
      sx8 kb[8];
#pragma unroll
      for (int mi = 0; mi < 8; ++mi)
        kb[mi] = *(const sx8*)&kbase[(size_t)(kt0 + mi * 16 + lr) * DH + kk * 32];
#pragma unroll
      for (int mi = 0; mi < 8; ++mi)
        st[mi] = __builtin_amdgcn_mfma_f32_16x16x32_bf16(kb[mi], qf[kk], st[mi], 0, 0, 0);
    }

    float pvv[8][4];
    float pmax = -1e30f;
    if (j < jmax) {   // bulk tiles: no causal mask
#pragma unroll
      for (int mi = 0; mi < 8; ++mi)
#pragma unroll
        for (int rg = 0; rg < 4; ++rg) {
          float val = st[mi][rg] * SCL;
          pvv[mi][rg] = val;
          pmax = fmaxf(pmax, val);
        }
    } else {          // final tile: causal mask
#pragma unroll
      for (int mi = 0; mi < 8; ++mi)
#pragma unroll
        for (int rg = 0; rg < 4; ++rg) {
          float val = st[mi][rg] * SCL;
          if ((kt0 + mi * 16 + lg * 4 + rg) > qg) val = -1e30f;
          pvv[mi][rg] = val;
          pmax = fmaxf(pmax, val);
        }
    }
    pmax = fmaxf(pmax, __shfl_xor(pmax, 16));
    pmax = fmaxf(pmax, __shfl_xor(pmax, 32));
    // defer-max (T13): rescale only when max grew > 11.5 (= e^8 in log2 units)
    if (!__all(pmax <= mrun + 11.5f)) {
      float mnew = fmaxf(mrun, pmax);
      float sc = exp2f(mrun - mnew);
      lrun *= sc;
#pragma unroll
      for (int dt = 0; dt < 4; ++dt)
#pragma unroll
        for (int rg = 0; rg < 4; ++rg) yacc[dt][rg] *= sc;
      mrun = mnew;
    }
    float ps = 0.f;
#pragma unroll
    for (int mi = 0; mi < 8; ++mi)
#pragma unroll
      for (int rg = 0; rg < 4; ++rg) {
        float e = exp2f(pvv[mi][rg] - mrun);
        pvv[mi][rg] = e;
        ps += e;
      }
    ps += __shfl_xor(ps, 16);
    ps += __shfl_xor(ps, 32);
    lrun += ps;

    // P -> per-wave LDS, packed via HW cvt_pk (T12 primitive)
#pragma unroll
    for (int mi = 0; mi < 8; ++mi)
#pragma unroll
      for (int rp = 0; rp < 2; ++rp) {
        unsigned pk = cvt_pk_bf16(pvv[mi][rp * 2], pvv[mi][rp * 2 + 1]);
        *(unsigned*)&Pw[wid][lr * 136 + mi * 16 + lg * 4 + rp * 2] = pk;
      }

    // PV: V^T-frags straight from global
#pragma unroll
    for (int kk = 0; kk < 4; ++kk) {
      sx8 pa = *(const sx8*)&Pw[wid][lr * 136 + kk * 32 + lg * 8];
      sx8 vb[4];
#pragma unroll
      for (int dt = 0; dt < 4; ++dt)
        vb[dt] = *(const sx8*)&vtbase[(size_t)(dt * 16 + lr) * T_SEQ + kt0 + kk * 32];
#pragma unroll
      for (int dt = 0; dt < 4; ++dt)
        yacc[dt] = __builtin_amdgcn_mfma_f32_16x16x32_bf16(vb[dt], pa, yacc[dt], 0, 0, 0);
    }
  }

  float inv = 1.0f / lrun;
  int tok = (bh >> 4) * T_SEQ + qg;
  int colbase = (bh & 15) * DH;
#pragma unroll
  for (int dt = 0; dt < 4; ++dt) {
    uint2 o;
    o.x = cvt_pk_bf16(yacc[dt][0] * inv, yacc[dt][1] * inv);
    o.y = cvt_pk_bf16(yacc[dt][2] * inv, yacc[dt][3] * inv);
    *(uint2*)&y[(size_t)tok * DM + colbase + dt * 16 + lg * 4] = o;
  }
}

// ---------------- launcher ----------------
extern "C" void kernel_launch(void* const* d_in, const int* in_sizes, int n_in,
                              void* d_out, int out_size, void* d_ws, size_t ws_size,
                              hipStream_t stream) {
  (void)in_sizes; (void)n_in; (void)out_size; (void)ws_size;
  const int*   idx     = (const int*)d_in[0];
  const float* tok_emb = (const float*)d_in[1];
  const float* pos_emb = (const float*)d_in[2];
  const float* ln1_s   = (const float*)d_in[3];
  const float* ln1_b   = (const float*)d_in[4];
  const float* qkv_w   = (const float*)d_in[5];
  const float* qkv_b   = (const float*)d_in[6];
  const float* out_w   = (const float*)d_in[7];
  const float* out_b   = (const float*)d_in[8];
  const float* ln2_s   = (const float*)d_in[9];
  const float* ln2_b   = (const float*)d_in[10];
  const float* mlp_w1  = (const float*)d_in[11];
  const float* mlp_b1  = (const float*)d_in[12];
  const float* mlp_w2  = (const float*)d_in[13];
  const float* mlp_b2  = (const float*)d_in[14];
  const float* lnf_s   = (const float*)d_in[15];
  const float* lnf_b   = (const float*)d_in[16];
  const float* head_w  = (const float*)d_in[17];

  char* p = (char*)d_ws;
  float* x          = (float*)p;          p += (size_t)NTOK * DM * 4;
  unsigned short* h = (unsigned short*)p; p += (size_t)NTOK * DM * 2;
  unsigned short* qkvb = (unsigned short*)p; p += (size_t)3 * NTOK * DM * 2;
  unsigned short* yb = (unsigned short*)p; p += (size_t)NTOK * DM * 2;
  unsigned short* m1 = (unsigned short*)p; p += (size_t)NTOK * DFF * 2;
  unsigned short* wt = (unsigned short*)p;                         // 64 MB (head)
  unsigned short* wtq  = wt;                                       // 3M elems
  unsigned short* wto  = wt + (size_t)3 * 1024 * 1024;             // 1M
  unsigned short* wtm1 = wt + (size_t)4 * 1024 * 1024;             // 4M
  unsigned short* wtm2 = wt + (size_t)8 * 1024 * 1024;             // 4M (24 MB total)
  unsigned short* part = (unsigned short*)(p + 32 * 1024 * 1024);  // bf16 partials

  dim3 blk(256);

  k_embed_ln<<<NTOK, blk, 0, stream>>>(idx, tok_emb, pos_emb, ln1_s, ln1_b, x, h);

  for (int l = 0; l < NL; ++l) {
    k_wtrans4<<<3072, blk, 0, stream>>>(qkv_w + (size_t)l * DM * 3 * DM,
                                        out_w + (size_t)l * DM * DM,
                                        mlp_w1 + (size_t)l * DM * DFF,
                                        mlp_w2 + (size_t)l * DFF * DM,
                                        wtq, wto, wtm1, wtm2);
    k_gemm<0><<<16 * 24, blk, 0, stream>>>(h, wtq, qkv_b + l * 3 * DM,
                                           nullptr, qkvb, nullptr, 3 * DM, DM, 24, 1);
    k_attn<<<512, blk, 0, stream>>>(qkvb, qkvb + (size_t)NTOK * DM,
                                    qkvb + (size_t)2 * NTOK * DM, yb);
    k_gemm<2><<<16 * 8 * 4, blk, 0, stream>>>(yb, wto, out_b + l * DM,
                                              part, nullptr, nullptr, DM, DM, 8, 4);
    k_reduce_ln<<<NTOK, blk, 0, stream>>>(part, x, ln2_s + l * DM, ln2_b + l * DM, h);
    k_gemm<1><<<16 * 32, blk, 0, stream>>>(h, wtm1, mlp_b1 + l * DFF,
                                           nullptr, m1, nullptr, DFF, DM, 32, 1);
    k_gemm<2><<<16 * 8 * 4, blk, 0, stream>>>(m1, wtm2, mlp_b2 + l * DM,
                                              part, nullptr, nullptr, DM, DFF, 8, 4);
    if (l < NL - 1)
      k_reduce_ln<<<NTOK, blk, 0, stream>>>(part, x, ln1_s + (l + 1) * DM, ln1_b + (l + 1) * DM, h);
    else
      k_reduce_ln<<<NTOK, blk, 0, stream>>>(part, x, lnf_s, lnf_b, h);
  }

  k_wtrans<<<dim3(DM / 64, VOCAB / 64), blk, 0, stream>>>(head_w, wt, DM, VOCAB);
  k_gemm256<<<1000, 512, 0, stream>>>(h, wt, (float*)d_out, VOCAB, DM);
}

// Round 11
// 1088.700 us; speedup vs baseline: 1.1951x; 1.1951x over previous
//
#include <hip/hip_runtime.h>

// GPT2-like forward, MI355X. Round 11:
// - attention: back to R8's LDS-staged structure (R10's direct-global regressed),
//   now with 3-barrier K/V pipelining: K(j+1) stages during PV(j), V(j+1) stages
//   after Vt release; vmcnt(4) separates K from V in-flight groups. LDS unchanged
//   (49.4 KB -> 3 blocks/CU preserved).
// - everything else identical to R8 (best: 1090 us)

#define T_SEQ 1024
#define NTOK  2048   // B*T
#define DM    1024
#define DFF   4096
#define NH    16
#define DH    64
#define NL    6
#define VOCAB 32000

typedef short sx8 __attribute__((ext_vector_type(8)));          // 8 bf16 (4 VGPR) MFMA frag
typedef float fx4 __attribute__((ext_vector_type(4)));          // MFMA acc
typedef unsigned short usx4 __attribute__((ext_vector_type(4)));
typedef unsigned int   uix4 __attribute__((ext_vector_type(4))); // 16B copy

__device__ __forceinline__ unsigned short f2bf(float f) {
  union { float f; unsigned u; } c; c.f = f;
  unsigned r = c.u + 0x7FFFu + ((c.u >> 16) & 1u);   // round-nearest-even
  return (unsigned short)(r >> 16);
}
__device__ __forceinline__ float bf2f(unsigned short u) {
  union { unsigned u; float f; } c; c.u = ((unsigned)u) << 16;
  return c.f;
}
// HW packed f32->2xbf16 convert (no builtin on gfx950; T12 primitive)
__device__ __forceinline__ unsigned cvt_pk_bf16(float lo, float hi) {
  unsigned r;
  asm("v_cvt_pk_bf16_f32 %0, %1, %2" : "=v"(r) : "v"(lo), "v"(hi));
  return r;
}

__device__ __forceinline__ void gload_lds16(const unsigned short* g, unsigned short* l) {
  __builtin_amdgcn_global_load_lds(
      (const __attribute__((address_space(1))) unsigned int*)g,
      (__attribute__((address_space(3))) unsigned int*)l, 16, 0, 0);
}

// bijective XCD-chunked swizzle (m204)
__device__ __forceinline__ int xcd_swizzle(int orig, int nwg) {
  int q = nwg >> 3, r = nwg & 7;
  int xcd = orig & 7, idx = orig >> 3;
  int base = (xcd < r) ? xcd * (q + 1) : r * (q + 1) + (xcd - r) * q;
  return base + idx;
}

// ---------------- fused embedding + ln1(layer0) ----------------
__global__ __launch_bounds__(256) void k_embed_ln(const int* __restrict__ idx,
                                                  const float* __restrict__ tok,
                                                  const float* __restrict__ pos,
                                                  const float* __restrict__ g,
                                                  const float* __restrict__ b,
                                                  float* __restrict__ x,
                                                  unsigned short* __restrict__ h) {
  int token = blockIdx.x;
  int t = token & (T_SEQ - 1);
  int id = idx[token];
  int tid = threadIdx.x;
  int c = tid * 4;
  float4 tv = *(const float4*)&tok[(size_t)id * DM + c];
  float4 pv = *(const float4*)&pos[(size_t)t * DM + c];
  float4 v;
  v.x = tv.x + pv.x; v.y = tv.y + pv.y; v.z = tv.z + pv.z; v.w = tv.w + pv.w;
  *(float4*)&x[(size_t)token * DM + c] = v;
  float s = v.x + v.y + v.z + v.w;
  float q = v.x * v.x + v.y * v.y + v.z * v.z + v.w * v.w;
  for (int off = 32; off > 0; off >>= 1) {
    s += __shfl_down(s, off);
    q += __shfl_down(q, off);
  }
  __shared__ float red[8];
  int wid = tid >> 6, lane = tid & 63;
  if (lane == 0) { red[wid] = s; red[4 + wid] = q; }
  __syncthreads();
  s = red[0] + red[1] + red[2] + red[3];
  q = red[4] + red[5] + red[6] + red[7];
  float mu = s * (1.0f / DM);
  float var = q * (1.0f / DM) - mu * mu;
  float rstd = rsqrtf(var + 1e-5f);
  float4 gg = *(const float4*)&g[c];
  float4 bb = *(const float4*)&b[c];
  uint2 o;
  o.x = cvt_pk_bf16((v.x - mu) * rstd * gg.x + bb.x, (v.y - mu) * rstd * gg.y + bb.y);
  o.y = cvt_pk_bf16((v.z - mu) * rstd * gg.z + bb.z, (v.w - mu) * rstd * gg.w + bb.w);
  *(uint2*)&h[(size_t)token * DM + c] = o;
}

// ------------- fused split-K(4) reduce (bf16 partials) + residual + layernorm -------------
__global__ __launch_bounds__(256) void k_reduce_ln(const unsigned short* __restrict__ part,
                                                   float* __restrict__ x,
                                                   const float* __restrict__ g,
                                                   const float* __restrict__ b,
                                                   unsigned short* __restrict__ h) {
  int row = blockIdx.x;
  int tid = threadIdx.x;
  int c = tid * 4;
  float4 v = *(const float4*)&x[(size_t)row * DM + c];
#pragma unroll
  for (int s4 = 0; s4 < 4; ++s4) {
    usx4 p = *(const usx4*)&part[((size_t)s4 * NTOK + row) * DM + c];
    v.x += bf2f(p[0]); v.y += bf2f(p[1]); v.z += bf2f(p[2]); v.w += bf2f(p[3]);
  }
  *(float4*)&x[(size_t)row * DM + c] = v;
  float s = v.x + v.y + v.z + v.w;
  float q = v.x * v.x + v.y * v.y + v.z * v.z + v.w * v.w;
  for (int off = 32; off > 0; off >>= 1) {
    s += __shfl_down(s, off);
    q += __shfl_down(q, off);
  }
  __shared__ float red[8];
  int wid = tid >> 6, lane = tid & 63;
  if (lane == 0) { red[wid] = s; red[4 + wid] = q; }
  __syncthreads();
  s = red[0] + red[1] + red[2] + red[3];
  q = red[4] + red[5] + red[6] + red[7];
  float mu = s * (1.0f / DM);
  float var = q * (1.0f / DM) - mu * mu;
  float rstd = rsqrtf(var + 1e-5f);
  float4 gg = *(const float4*)&g[c];
  float4 bb = *(const float4*)&b[c];
  uint2 o;
  o.x = cvt_pk_bf16((v.x - mu) * rstd * gg.x + bb.x, (v.y - mu) * rstd * gg.y + bb.y);
  o.y = cvt_pk_bf16((v.z - mu) * rstd * gg.z + bb.z, (v.w - mu) * rstd * gg.w + bb.w);
  *(uint2*)&h[(size_t)row * DM + c] = o;
}

// ---------------- weight convert+transpose core ----------------
__device__ __forceinline__ void wtrans_body(const float* __restrict__ W,
                                            unsigned short* __restrict__ WT,
                                            int K, int N, int k0, int n0, int tid) {
  __shared__ float t[64][68];
#pragma unroll
  for (int i = 0; i < 4; ++i) {
    int chunk = i * 256 + tid;
    int r = chunk >> 4, c = (chunk & 15) << 2;
    float4 v = *(const float4*)&W[(size_t)(k0 + r) * N + n0 + c];
    t[r][c] = v.x; t[r][c + 1] = v.y; t[r][c + 2] = v.z; t[r][c + 3] = v.w;
  }
  __syncthreads();
#pragma unroll
  for (int i = 0; i < 4; ++i) {
    int chunk = i * 256 + tid;
    int n = chunk >> 4, c = (chunk & 15) << 2;
    uint2 o;
    o.x = cvt_pk_bf16(t[c][n], t[c + 1][n]);
    o.y = cvt_pk_bf16(t[c + 2][n], t[c + 3][n]);
    *(uint2*)&WT[(size_t)(n0 + n) * K + k0 + c] = o;
  }
}

// standalone (head)
__global__ __launch_bounds__(256) void k_wtrans(const float* __restrict__ W,
                                                unsigned short* __restrict__ WT,
                                                int K, int N) {
  wtrans_body(W, WT, K, N, blockIdx.x * 64, blockIdx.y * 64, threadIdx.x);
}

// all 4 per-layer weights in one launch (segmented block ranges)
__global__ __launch_bounds__(256) void k_wtrans4(const float* __restrict__ W0,
                                                 const float* __restrict__ W1,
                                                 const float* __restrict__ W2,
                                                 const float* __restrict__ W3,
                                                 unsigned short* __restrict__ T0,
                                                 unsigned short* __restrict__ T1,
                                                 unsigned short* __restrict__ T2,
                                                 unsigned short* __restrict__ T3) {
  int id = blockIdx.x;
  const float* W; unsigned short* WT; int K, N, lid;
  if (id < 768)       { W = W0; WT = T0; K = 1024; N = 3072; lid = id; }
  else if (id < 1024) { W = W1; WT = T1; K = 1024; N = 1024; lid = id - 768; }
  else if (id < 2048) { W = W2; WT = T2; K = 1024; N = 4096; lid = id - 1024; }
  else                { W = W3; WT = T3; K = 4096; N = 1024; lid = id - 2048; }
  int kb = K >> 6;
  wtrans_body(W, WT, K, N, (lid % kb) * 64, (lid / kb) * 64, threadIdx.x);
}

// ---------------- 128x128 GEMM, T3 2-phase prefetch ----------------
// EPI: 0=qkv scatter(+bias, V transposed), 1=gelu(+bias)->bf16, 2=+bias -> bf16 partials
template <int EPI>
__global__ __launch_bounds__(256) void k_gemm(const unsigned short* __restrict__ A,
                                              const unsigned short* __restrict__ BT,
                                              const float* __restrict__ bias,
                                              unsigned short* __restrict__ part,
                                              unsigned short* __restrict__ outb,
                                              float* __restrict__ outf,
                                              int N, int K, int NT, int KS) {
  __shared__ unsigned short As[2][128 * 64];
  __shared__ unsigned short Bs[2][128 * 64];
  int tid = threadIdx.x;
  int wid = tid >> 6, lane = tid & 63;
  int lr = lane & 15, lg = lane >> 4;

  int id = xcd_swizzle(blockIdx.x, gridDim.x);
  int mt = id & 15;
  int rest = id >> 4;
  int nt = rest % NT;
  int ks = rest / NT;
  int m0 = mt * 128, n0 = nt * 128;
  int Kslice = K / KS;
  int kbeg = ks * Kslice;
  int nk = Kslice >> 6;

  int wm = (wid >> 1) * 64, wn = (wid & 1) * 64;

  fx4 acc[4][4] = {};

#define GSTAGE(buf, kt)                                                         \
  {                                                                             \
    _Pragma("unroll")                                                           \
    for (int i = 0; i < 4; ++i) {                                               \
      int chunk = i * 256 + tid;                                                \
      int r = chunk >> 3, slot = chunk & 7;                                     \
      int c = ((slot ^ (r & 7)) << 3);                                          \
      gload_lds16(&A[(size_t)(m0 + r) * K + (kt) + c], &As[buf][chunk << 3]);   \
      gload_lds16(&BT[(size_t)(n0 + r) * K + (kt) + c], &Bs[buf][chunk << 3]);  \
    }                                                                           \
  }

  GSTAGE(0, kbeg);
  for (int ik = 0; ik < nk; ++ik) {
    int cur = ik & 1;
    if (ik + 1 < nk) {
      GSTAGE(cur ^ 1, kbeg + (ik + 1) * 64);
      asm volatile("s_waitcnt vmcnt(8)" ::: "memory");   // oldest 8 = current tile
    } else {
      asm volatile("s_waitcnt vmcnt(0)" ::: "memory");
    }
    __builtin_amdgcn_sched_barrier(0);
    __builtin_amdgcn_s_barrier();                        // current tile visible to all
    __builtin_amdgcn_sched_barrier(0);
#pragma unroll
    for (int kk = 0; kk < 2; ++kk) {
      int slotz = (kk * 4 + lg) ^ (lr & 7);
      sx8 fa[4], fb[4];
#pragma unroll
      for (int mi = 0; mi < 4; ++mi)
        fa[mi] = *(const sx8*)&As[cur][(wm + mi * 16 + lr) * 64 + slotz * 8];
#pragma unroll
      for (int ni = 0; ni < 4; ++ni)
        fb[ni] = *(const sx8*)&Bs[cur][(wn + ni * 16 + lr) * 64 + slotz * 8];
#pragma unroll
      for (int mi = 0; mi < 4; ++mi)
#pragma unroll
        for (int ni = 0; ni < 4; ++ni)
          acc[mi][ni] = __builtin_amdgcn_mfma_f32_16x16x32_bf16(fb[ni], fa[mi], acc[mi][ni], 0, 0, 0);
    }
    asm volatile("s_waitcnt lgkmcnt(0)" ::: "memory");   // my ds_reads landed
    __builtin_amdgcn_sched_barrier(0);
    __builtin_amdgcn_s_barrier();                        // safe to overwrite cur next iter
  }
#undef GSTAGE

#pragma unroll
  for (int ni = 0; ni < 4; ++ni) {
    int col0 = n0 + wn + ni * 16 + lg * 4;
    float4 bv = {0.f, 0.f, 0.f, 0.f};
    if (bias && ks == 0) bv = *(const float4*)&bias[col0];
#pragma unroll
    for (int mi = 0; mi < 4; ++mi) {
      int row = m0 + wm + mi * 16 + lr;
      float v0 = acc[mi][ni][0] + bv.x;
      float v1 = acc[mi][ni][1] + bv.y;
      float v2 = acc[mi][ni][2] + bv.z;
      float v3 = acc[mi][ni][3] + bv.w;
      if constexpr (EPI == 0) {
        int bb = row >> 10, tt = row & 1023;
        if (col0 < 2048) {
          int which = col0 >> 10;
          int hc = col0 & 1023;
          uint2 o = {cvt_pk_bf16(v0, v1), cvt_pk_bf16(v2, v3)};
          *(uint2*)&outb[(size_t)which * NTOK * DM +
                         (((size_t)bb * NH + (hc >> 6)) * T_SEQ + tt) * DH + (hc & 63)] = o;
        } else {
          int dc = col0 - 2048;
          unsigned short* vt = outb + (size_t)2 * NTOK * DM;
          size_t base = (((size_t)bb * NH + (dc >> 6)) * DH + (dc & 63)) * T_SEQ + tt;
          vt[base] = f2bf(v0);
          vt[base + T_SEQ] = f2bf(v1);
          vt[base + 2 * T_SEQ] = f2bf(v2);
          vt[base + 3 * T_SEQ] = f2bf(v3);
        }
      } else if constexpr (EPI == 1) {
        float g0 = 0.5f * v0 * (1.0f + erff(v0 * 0.70710678f));
        float g1 = 0.5f * v1 * (1.0f + erff(v1 * 0.70710678f));
        float g2 = 0.5f * v2 * (1.0f + erff(v2 * 0.70710678f));
        float g3 = 0.5f * v3 * (1.0f + erff(v3 * 0.70710678f));
        uint2 o = {cvt_pk_bf16(g0, g1), cvt_pk_bf16(g2, g3)};
        *(uint2*)&outb[(size_t)row * N + col0] = o;
      } else {  // bf16 partial slice (split-K)
        uint2 o = {cvt_pk_bf16(v0, v1), cvt_pk_bf16(v2, v3)};
        *(uint2*)&part[((size_t)ks * NTOK + row) * DM + col0] = o;
      }
    }
  }
}

// ---------------- 256x256 8-phase GEMM (head) — R8 proven version ----------------
#define LDSUB(buf, ab, kk) (lds + (((buf) * 2 + (ab)) * 2 + (kk)) * 8192)

__device__ __forceinline__ void stage_half(const unsigned short* g, int rowstride,
                                           unsigned short* ldsbase, int tid, int k0) {
#pragma unroll
  for (int r = 0; r < 2; ++r) {
    int chunk = r * 512 + tid;
    int row = chunk >> 2, slot = chunk & 3;
    gload_lds16(g + (size_t)row * rowstride + k0 + ((slot ^ ((row >> 1) & 3)) << 3),
                ldsbase + (chunk << 3));
  }
}

__global__ __launch_bounds__(512, 2) void k_gemm256(const unsigned short* __restrict__ A,
                                                    const unsigned short* __restrict__ BT,
                                                    float* __restrict__ outf,
                                                    int N, int K) {
  __shared__ unsigned short lds[8 * 8192];   // 128 KB
  int tid = threadIdx.x;
  int wid = tid >> 6, lane = tid & 63;
  int lr = lane & 15, lg = lane >> 4;
  int wm2 = wid >> 2, wn4 = wid & 3;
  int id = xcd_swizzle(blockIdx.x, gridDim.x);
  int mt = id & 7, nt = id >> 3;          // mt fastest: 8 blocks share B panel
  int m0 = mt * 256, n0 = nt * 256;
  const unsigned short* Ab = A + (size_t)m0 * K;
  const unsigned short* Bb = BT + (size_t)n0 * K;
  int NIT = K >> 7;                        // 2 K-tiles (of 64) per iteration
  int swz = (lg ^ ((lr >> 1) & 3)) << 3;   // matches stage_half swizzle
  float* obase = outf + (size_t)(m0 + wm2 * 128 + lr) * N + n0 + wn4 * 64 + lg * 4;

  fx4 acc[8][4] = {};

  // prologue: tile0 {A0,B0,A1,B1}, tile1 {A0,B0,A1} = 7 half-tiles (14 loads)
  stage_half(Ab, K, LDSUB(0, 0, 0), tid, 0);
  stage_half(Bb, K, LDSUB(0, 1, 0), tid, 0);
  stage_half(Ab, K, LDSUB(0, 0, 1), tid, 32);
  stage_half(Bb, K, LDSUB(0, 1, 1), tid, 32);
  stage_half(Ab, K, LDSUB(1, 0, 0), tid, 64);
  stage_half(Bb, K, LDSUB(1, 1, 0), tid, 64);
  stage_half(Ab, K, LDSUB(1, 0, 1), tid, 96);
  asm volatile("s_waitcnt vmcnt(6)" ::: "memory");   // tile0 fully staged
  __builtin_amdgcn_s_barrier();

#define PHASE(BUF, KK, NHH, LOADA, STG, VMW)                                         \
  {                                                                                  \
    if (LOADA) {                                                                     \
      const unsigned short* sA = LDSUB(BUF, 0, KK);                                  \
      _Pragma("unroll")                                                              \
      for (int mi = 0; mi < 8; ++mi)                                                 \
        fa[mi] = *(const sx8*)&sA[(wm2 * 128 + mi * 16 + lr) * 32 + swz];            \
    }                                                                                \
    {                                                                                \
      const unsigned short* sB = LDSUB(BUF, 1, KK);                                  \
      _Pragma("unroll")                                                              \
      for (int j = 0; j < 2; ++j)                                                    \
        fb[j] = *(const sx8*)&sB[(wn4 * 64 + (NHH) * 32 + j * 16 + lr) * 32 + swz];  \
    }                                                                                \
    STG;                                                                             \
    VMW;                                                                             \
    __builtin_amdgcn_sched_barrier(0);                                               \
    __builtin_amdgcn_s_barrier();                                                    \
    asm volatile("s_waitcnt lgkmcnt(0)" ::: "memory");                               \
    __builtin_amdgcn_sched_barrier(0);                                               \
    __builtin_amdgcn_s_setprio(1);                                                   \
    _Pragma("unroll")                                                                \
    for (int mi = 0; mi < 8; ++mi) {                                                 \
      acc[mi][(NHH) * 2 + 0] = __builtin_amdgcn_mfma_f32_16x16x32_bf16(              \
          fb[0], fa[mi], acc[mi][(NHH) * 2 + 0], 0, 0, 0);                           \
      acc[mi][(NHH) * 2 + 1] = __builtin_amdgcn_mfma_f32_16x16x32_bf16(              \
          fb[1], fa[mi], acc[mi][(NHH) * 2 + 1], 0, 0, 0);                           \
    }                                                                                \
    __builtin_amdgcn_s_setprio(0);                                                   \
    __builtin_amdgcn_sched_barrier(0);                                               \
    __builtin_amdgcn_s_barrier();                                                    \
  }

  for (int it = 0; it < NIT; ++it) {
    bool st = (it < NIT - 1);
    bool last = (it == NIT - 1);
    int t1k = (2 * it + 1) * 64;
    int t2k = (2 * it + 2) * 64;
    int t3k = (2 * it + 3) * 64;
    sx8 fa[8], fb[2];

    PHASE(0, 0, 0, true,
          { stage_half(Bb, K, LDSUB(1, 1, 1), tid, t1k + 32); }, {});
    PHASE(0, 0, 1, false,
          { if (st) stage_half(Ab, K, LDSUB(0, 0, 0), tid, t2k); }, {});
    PHASE(0, 1, 0, true,
          { if (st) stage_half(Bb, K, LDSUB(0, 1, 0), tid, t2k); }, {});
    PHASE(0, 1, 1, false,
          { if (st) stage_half(Ab, K, LDSUB(0, 0, 1), tid, t2k + 32); },
          { if (last) { asm volatile("s_waitcnt vmcnt(0)" ::: "memory"); }
            else      { asm volatile("s_waitcnt vmcnt(6)" ::: "memory"); } });
    PHASE(1, 0, 0, true,
          { if (st) stage_half(Bb, K, LDSUB(0, 1, 1), tid, t2k + 32); }, {});
    PHASE(1, 0, 1, false,
          { if (st) stage_half(Ab, K, LDSUB(1, 0, 0), tid, t3k); }, {});
    PHASE(1, 1, 0, true,
          { if (st) stage_half(Bb, K, LDSUB(1, 1, 0), tid, t3k); }, {});
    // split epilogue: nj 0,1 final after p7 -> store overlapped with p8
    if (last) {
#pragma unroll
      for (int mi = 0; mi < 8; ++mi) {
        *(float4*)(obase + (size_t)mi * 16 * N) =
            (float4){acc[mi][0][0], acc[mi][0][1], acc[mi][0][2], acc[mi][0][3]};
        *(float4*)(obase + (size_t)mi * 16 * N + 16) =
            (float4){acc[mi][1][0], acc[mi][1][1], acc[mi][1][2], acc[mi][1][3]};
      }
    }
    PHASE(1, 1, 1, false,
          { if (st) stage_half(Ab, K, LDSUB(1, 0, 1), tid, t3k + 32); },
          { if (!last) { asm volatile("s_waitcnt vmcnt(6)" ::: "memory"); } });
  }
#undef PHASE

  // remaining quadrants nj 2,3
#pragma unroll
  for (int mi = 0; mi < 8; ++mi) {
    *(float4*)(obase + (size_t)mi * 16 * N + 32) =
        (float4){acc[mi][2][0], acc[mi][2][1], acc[mi][2][2], acc[mi][2][3]};
    *(float4*)(obase + (size_t)mi * 16 * N + 48) =
        (float4){acc[mi][3][0], acc[mi][3][1], acc[mi][3][2], acc[mi][3][3]};
  }
}

// ---------------- flash attention, KVBLK=128, pipelined K/V staging ----------------
// Per tile j: [K(j) ready at entry, V(j) in flight]
//   QK^T + softmax;  vmcnt(0)+barrier  (V landed; all Ks reads done)
//   stage K(j+1) into Ks (safe: Ks free);  PV
//   lgkmcnt(0)+barrier (Vt reads done); stage V(j+1); vmcnt(4)+barrier (K(j+1) landed)
__global__ __launch_bounds__(256) void k_attn(const unsigned short* __restrict__ gq,
                                              const unsigned short* __restrict__ gk,
                                              const unsigned short* __restrict__ gvt,
                                              unsigned short* __restrict__ y) {
  __shared__ unsigned short Ks[128 * 64];
  __shared__ unsigned short Vt[64 * 128];
  __shared__ unsigned short Pw[4][16 * 136];
  int id = xcd_swizzle(blockIdx.x, gridDim.x);
  int bh = id >> 4, qt = 15 - (id & 15);
  int tid = threadIdx.x, wid = tid >> 6, lane = tid & 63;
  int lr = lane & 15, lg = lane >> 4;
  int q0 = qt * 64 + wid * 16;
  int qg = q0 + lr;
  const float SCL = 0.125f * 1.44269504f;   // 1/sqrt(64) * log2(e)

#define STAGE_K(kt0)                                                                  \
  {                                                                                   \
    _Pragma("unroll")                                                                 \
    for (int i = 0; i < 4; ++i) {                                                     \
      int chunk = i * 256 + tid;                                                      \
      int r = chunk >> 3, s = chunk & 7;                                              \
      gload_lds16(&gk[((size_t)bh * T_SEQ + (kt0) + r) * DH + ((s ^ (r & 7)) << 3)],  \
                  &Ks[chunk << 3]);                                                   \
    }                                                                                 \
  }
#define STAGE_V(kt0)                                                                  \
  {                                                                                   \
    _Pragma("unroll")                                                                 \
    for (int i = 0; i < 4; ++i) {                                                     \
      int chunk = i * 256 + tid;                                                      \
      int r = chunk >> 4, s = chunk & 15;                                             \
      gload_lds16(&gvt[((size_t)bh * DH + r) * T_SEQ + (kt0) + ((s ^ (r & 15)) << 3)],\
                  &Vt[chunk << 3]);                                                   \
    }                                                                                 \
  }

  sx8 qf[2];
  {
    const unsigned short* qp = gq + ((size_t)bh * T_SEQ + qg) * DH + lg * 8;
    qf[0] = *(const sx8*)qp;
    qf[1] = *(const sx8*)(qp + 32);
  }

  fx4 yacc[4] = {};
  float mrun = -1e30f, lrun = 0.f;   // lane-local (q-row = lr), log2 domain

  // prologue: K(0) then V(0); wait K only (V drains at first tile's vmcnt(0))
  STAGE_K(0);
  STAGE_V(0);
  asm volatile("s_waitcnt vmcnt(4)" ::: "memory");
  __builtin_amdgcn_sched_barrier(0);
  __builtin_amdgcn_s_barrier();

  int jmax = qt >> 1;
  for (int j = 0; j <= jmax; ++j) {
    int kt0 = j * 128;
    bool more = (j < jmax);

    // S^T = K Q^T
    fx4 st[8] = {};
#pragma unroll
    for (int kk = 0; kk < 2; ++kk) {
      int slotz = (kk * 4 + lg) ^ (lr & 7);
#pragma unroll
      for (int mi = 0; mi < 8; ++mi) {
        sx8 kb = *(const sx8*)&Ks[(mi * 16 + lr) * 64 + slotz * 8];
        st[mi] = __builtin_amdgcn_mfma_f32_16x16x32_bf16(kb, qf[kk], st[mi], 0, 0, 0);
      }
    }

    float pvv[8][4];
    float pmax = -1e30f;
    if (j < jmax) {   // bulk tiles: no causal mask
#pragma unroll
      for (int mi = 0; mi < 8; ++mi)
#pragma unroll
        for (int rg = 0; rg < 4; ++rg) {
          float val = st[mi][rg] * SCL;
          pvv[mi][rg] = val;
          pmax = fmaxf(pmax, val);
        }
    } else {          // final tile: causal mask
#pragma unroll
      for (int mi = 0; mi < 8; ++mi)
#pragma unroll
        for (int rg = 0; rg < 4; ++rg) {
          float val = st[mi][rg] * SCL;
          if ((kt0 + mi * 16 + lg * 4 + rg) > qg) val = -1e30f;
          pvv[mi][rg] = val;
          pmax = fmaxf(pmax, val);
        }
    }
    pmax = fmaxf(pmax, __shfl_xor(pmax, 16));
    pmax = fmaxf(pmax, __shfl_xor(pmax, 32));
    // defer-max (T13): rescale only when max grew > 11.5 (= e^8 in log2 units)
    if (!__all(pmax <= mrun + 11.5f)) {
      float mnew = fmaxf(mrun, pmax);
      float sc = exp2f(mrun - mnew);
      lrun *= sc;
#pragma unroll
      for (int dt = 0; dt < 4; ++dt)
#pragma unroll
        for (int rg = 0; rg < 4; ++rg) yacc[dt][rg] *= sc;
      mrun = mnew;
    }
    float ps = 0.f;
#pragma unroll
    for (int mi = 0; mi < 8; ++mi)
#pragma unroll
      for (int rg = 0; rg < 4; ++rg) {
        float e = exp2f(pvv[mi][rg] - mrun);
        pvv[mi][rg] = e;
        ps += e;
      }
    ps += __shfl_xor(ps, 16);
    ps += __shfl_xor(ps, 32);
    lrun += ps;

    // P -> per-wave LDS, packed via HW cvt_pk (T12 primitive)
#pragma unroll
    for (int mi = 0; mi < 8; ++mi)
#pragma unroll
      for (int rp = 0; rp < 2; ++rp) {
        unsigned pk = cvt_pk_bf16(pvv[mi][rp * 2], pvv[mi][rp * 2 + 1]);
        *(unsigned*)&Pw[wid][lr * 136 + mi * 16 + lg * 4 + rp * 2] = pk;
      }

    // V(j) landed + all waves' Ks reads complete
    asm volatile("s_waitcnt vmcnt(0)" ::: "memory");
    __builtin_amdgcn_sched_barrier(0);
    __builtin_amdgcn_s_barrier();
    __builtin_amdgcn_sched_barrier(0);

    // stage next K into Ks while PV computes (Ks free after barrier above)
    if (more) STAGE_K(kt0 + 128);

    // PV
#pragma unroll
    for (int kk = 0; kk < 4; ++kk) {
      sx8 pa = *(const sx8*)&Pw[wid][lr * 136 + kk * 32 + lg * 8];
      int slotz = (kk * 4 + lg) ^ lr;
#pragma unroll
      for (int dt = 0; dt < 4; ++dt) {
        sx8 vb = *(const sx8*)&Vt[(dt * 16 + lr) * 128 + slotz * 8];
        yacc[dt] = __builtin_amdgcn_mfma_f32_16x16x32_bf16(vb, pa, yacc[dt], 0, 0, 0);
      }
    }

    if (more) {
      // all waves done reading Vt -> stage next V; then confirm K(j+1) landed
      asm volatile("s_waitcnt lgkmcnt(0)" ::: "memory");
      __builtin_amdgcn_sched_barrier(0);
      __builtin_amdgcn_s_barrier();
      __builtin_amdgcn_sched_barrier(0);
      STAGE_V(kt0 + 128);
      asm volatile("s_waitcnt vmcnt(4)" ::: "memory");   // 4 newest (V) stay in flight
      __builtin_amdgcn_sched_barrier(0);
      __builtin_amdgcn_s_barrier();
    }
  }
#undef STAGE_K
#undef STAGE_V

  float inv = 1.0f / lrun;
  int tok = (bh >> 4) * T_SEQ + qg;
  int colbase = (bh & 15) * DH;
#pragma unroll
  for (int dt = 0; dt < 4; ++dt) {
    uint2 o;
    o.x = cvt_pk_bf16(yacc[dt][0] * inv, yacc[dt][1] * inv);
    o.y = cvt_pk_bf16(yacc[dt][2] * inv, yacc[dt][3] * inv);
    *(uint2*)&y[(size_t)tok * DM + colbase + dt * 16 + lg * 4] = o;
  }
}

// ---------------- launcher ----------------
extern "C" void kernel_launch(void* const* d_in, const int* in_sizes, int n_in,
                              void* d_out, int out_size, void* d_ws, size_t ws_size,
                              hipStream_t stream) {
  (void)in_sizes; (void)n_in; (void)out_size; (void)ws_size;
  const int*   idx     = (const int*)d_in[0];
  const float* tok_emb = (const float*)d_in[1];
  const float* pos_emb = (const float*)d_in[2];
  const float* ln1_s   = (const float*)d_in[3];
  const float* ln1_b   = (const float*)d_in[4];
  const float* qkv_w   = (const float*)d_in[5];
  const float* qkv_b   = (const float*)d_in[6];
  const float* out_w   = (const float*)d_in[7];
  const float* out_b   = (const float*)d_in[8];
  const float* ln2_s   = (const float*)d_in[9];
  const float* ln2_b   = (const float*)d_in[10];
  const float* mlp_w1  = (const float*)d_in[11];
  const float* mlp_b1  = (const float*)d_in[12];
  const float* mlp_w2  = (const float*)d_in[13];
  const float* mlp_b2  = (const float*)d_in[14];
  const float* lnf_s   = (const float*)d_in[15];
  const float* lnf_b   = (const float*)d_in[16];
  const float* head_w  = (const float*)d_in[17];

  char* p = (char*)d_ws;
  float* x          = (float*)p;          p += (size_t)NTOK * DM * 4;
  unsigned short* h = (unsigned short*)p; p += (size_t)NTOK * DM * 2;
  unsigned short* qkvb = (unsigned short*)p; p += (size_t)3 * NTOK * DM * 2;
  unsigned short* yb = (unsigned short*)p; p += (size_t)NTOK * DM * 2;
  unsigned short* m1 = (unsigned short*)p; p += (size_t)NTOK * DFF * 2;
  unsigned short* wt = (unsigned short*)p;                         // 64 MB (head)
  unsigned short* wtq  = wt;                                       // 3M elems
  unsigned short* wto  = wt + (size_t)3 * 1024 * 1024;             // 1M
  unsigned short* wtm1 = wt + (size_t)4 * 1024 * 1024;             // 4M
  unsigned short* wtm2 = wt + (size_t)8 * 1024 * 1024;             // 4M (24 MB total)
  unsigned short* part = (unsigned short*)(p + 32 * 1024 * 1024);  // bf16 partials

  dim3 blk(256);

  k_embed_ln<<<NTOK, blk, 0, stream>>>(idx, tok_emb, pos_emb, ln1_s, ln1_b, x, h);

  for (int l = 0; l < NL; ++l) {
    k_wtrans4<<<3072, blk, 0, stream>>>(qkv_w + (size_t)l * DM * 3 * DM,
                                        out_w + (size_t)l * DM * DM,
                                        mlp_w1 + (size_t)l * DM * DFF,
                                        mlp_w2 + (size_t)l * DFF * DM,
                                        wtq, wto, wtm1, wtm2);
    k_gemm<0><<<16 * 24, blk, 0, stream>>>(h, wtq, qkv_b + l * 3 * DM,
                                           nullptr, qkvb, nullptr, 3 * DM, DM, 24, 1);
    k_attn<<<512, blk, 0, stream>>>(qkvb, qkvb + (size_t)NTOK * DM,
                                    qkvb + (size_t)2 * NTOK * DM, yb);
    k_gemm<2><<<16 * 8 * 4, blk, 0, stream>>>(yb, wto, out_b + l * DM,
                                              part, nullptr, nullptr, DM, DM, 8, 4);
    k_reduce_ln<<<NTOK, blk, 0, stream>>>(part, x, ln2_s + l * DM, ln2_b + l * DM, h);
    k_gemm<1><<<16 * 32, blk, 0, stream>>>(h, wtm1, mlp_b1 + l * DFF,
                                           nullptr, m1, nullptr, DFF, DM, 32, 1);
    k_gemm<2><<<16 * 8 * 4, blk, 0, stream>>>(m1, wtm2, mlp_b2 + l * DM,
                                              part, nullptr, nullptr, DM, DFF, 8, 4);
    if (l < NL - 1)
      k_reduce_ln<<<NTOK, blk, 0, stream>>>(part, x, ln1_s + (l + 1) * DM, ln1_b + (l + 1) * DM, h);
    else
      k_reduce_ln<<<NTOK, blk, 0, stream>>>(part, x, lnf_s, lnf_b, h);
  }

  k_wtrans<<<dim3(DM / 64, VOCAB / 64), blk, 0, stream>>>(head_w, wt, DM, VOCAB);
  k_gemm256<<<1000, 512, 0, stream>>>(h, wt, (float*)d_out, VOCAB, DM);
}

// Round 12
// 1088.134 us; speedup vs baseline: 1.1957x; 1.0005x over previous
//
#include <hip/hip_runtime.h>

// GPT2-like forward, MI355X. Round 12:
// - softmax diet: (1) QK scale folded into Q at qkv epilogue, (2) P row-sum via
//   MFMA ones-trick (replaces 32 fadd + 2 shfl), (3) uint2 P-writes (8 ds_write_b64)
// - everything else identical to R11 (head 8-phase, 2-phase layer GEMMs, pipelined attn staging)

#define T_SEQ 1024
#define NTOK  2048   // B*T
#define DM    1024
#define DFF   4096
#define NH    16
#define DH    64
#define NL    6
#define VOCAB 32000

typedef short sx8 __attribute__((ext_vector_type(8)));          // 8 bf16 (4 VGPR) MFMA frag
typedef float fx4 __attribute__((ext_vector_type(4)));          // MFMA acc
typedef unsigned short usx4 __attribute__((ext_vector_type(4)));
typedef unsigned int   uix4 __attribute__((ext_vector_type(4))); // 16B copy

__device__ __forceinline__ unsigned short f2bf(float f) {
  union { float f; unsigned u; } c; c.f = f;
  unsigned r = c.u + 0x7FFFu + ((c.u >> 16) & 1u);   // round-nearest-even
  return (unsigned short)(r >> 16);
}
__device__ __forceinline__ float bf2f(unsigned short u) {
  union { unsigned u; float f; } c; c.u = ((unsigned)u) << 16;
  return c.f;
}
// HW packed f32->2xbf16 convert (no builtin on gfx950; T12 primitive)
__device__ __forceinline__ unsigned cvt_pk_bf16(float lo, float hi) {
  unsigned r;
  asm("v_cvt_pk_bf16_f32 %0, %1, %2" : "=v"(r) : "v"(lo), "v"(hi));
  return r;
}

__device__ __forceinline__ void gload_lds16(const unsigned short* g, unsigned short* l) {
  __builtin_amdgcn_global_load_lds(
      (const __attribute__((address_space(1))) unsigned int*)g,
      (__attribute__((address_space(3))) unsigned int*)l, 16, 0, 0);
}

// bijective XCD-chunked swizzle (m204)
__device__ __forceinline__ int xcd_swizzle(int orig, int nwg) {
  int q = nwg >> 3, r = nwg & 7;
  int xcd = orig & 7, idx = orig >> 3;
  int base = (xcd < r) ? xcd * (q + 1) : r * (q + 1) + (xcd - r) * q;
  return base + idx;
}

// ---------------- fused embedding + ln1(layer0) ----------------
__global__ __launch_bounds__(256) void k_embed_ln(const int* __restrict__ idx,
                                                  const float* __restrict__ tok,
                                                  const float* __restrict__ pos,
                                                  const float* __restrict__ g,
                                                  const float* __restrict__ b,
                                                  float* __restrict__ x,
                                                  unsigned short* __restrict__ h) {
  int token = blockIdx.x;
  int t = token & (T_SEQ - 1);
  int id = idx[token];
  int tid = threadIdx.x;
  int c = tid * 4;
  float4 tv = *(const float4*)&tok[(size_t)id * DM + c];
  float4 pv = *(const float4*)&pos[(size_t)t * DM + c];
  float4 v;
  v.x = tv.x + pv.x; v.y = tv.y + pv.y; v.z = tv.z + pv.z; v.w = tv.w + pv.w;
  *(float4*)&x[(size_t)token * DM + c] = v;
  float s = v.x + v.y + v.z + v.w;
  float q = v.x * v.x + v.y * v.y + v.z * v.z + v.w * v.w;
  for (int off = 32; off > 0; off >>= 1) {
    s += __shfl_down(s, off);
    q += __shfl_down(q, off);
  }
  __shared__ float red[8];
  int wid = tid >> 6, lane = tid & 63;
  if (lane == 0) { red[wid] = s; red[4 + wid] = q; }
  __syncthreads();
  s = red[0] + red[1] + red[2] + red[3];
  q = red[4] + red[5] + red[6] + red[7];
  float mu = s * (1.0f / DM);
  float var = q * (1.0f / DM) - mu * mu;
  float rstd = rsqrtf(var + 1e-5f);
  float4 gg = *(const float4*)&g[c];
  float4 bb = *(const float4*)&b[c];
  uint2 o;
  o.x = cvt_pk_bf16((v.x - mu) * rstd * gg.x + bb.x, (v.y - mu) * rstd * gg.y + bb.y);
  o.y = cvt_pk_bf16((v.z - mu) * rstd * gg.z + bb.z, (v.w - mu) * rstd * gg.w + bb.w);
  *(uint2*)&h[(size_t)token * DM + c] = o;
}

// ------------- fused split-K(4) reduce (bf16 partials) + residual + layernorm -------------
__global__ __launch_bounds__(256) void k_reduce_ln(const unsigned short* __restrict__ part,
                                                   float* __restrict__ x,
                                                   const float* __restrict__ g,
                                                   const float* __restrict__ b,
                                                   unsigned short* __restrict__ h) {
  int row = blockIdx.x;
  int tid = threadIdx.x;
  int c = tid * 4;
  float4 v = *(const float4*)&x[(size_t)row * DM + c];
#pragma unroll
  for (int s4 = 0; s4 < 4; ++s4) {
    usx4 p = *(const usx4*)&part[((size_t)s4 * NTOK + row) * DM + c];
    v.x += bf2f(p[0]); v.y += bf2f(p[1]); v.z += bf2f(p[2]); v.w += bf2f(p[3]);
  }
  *(float4*)&x[(size_t)row * DM + c] = v;
  float s = v.x + v.y + v.z + v.w;
  float q = v.x * v.x + v.y * v.y + v.z * v.z + v.w * v.w;
  for (int off = 32; off > 0; off >>= 1) {
    s += __shfl_down(s, off);
    q += __shfl_down(q, off);
  }
  __shared__ float red[8];
  int wid = tid >> 6, lane = tid & 63;
  if (lane == 0) { red[wid] = s; red[4 + wid] = q; }
  __syncthreads();
  s = red[0] + red[1] + red[2] + red[3];
  q = red[4] + red[5] + red[6] + red[7];
  float mu = s * (1.0f / DM);
  float var = q * (1.0f / DM) - mu * mu;
  float rstd = rsqrtf(var + 1e-5f);
  float4 gg = *(const float4*)&g[c];
  float4 bb = *(const float4*)&b[c];
  uint2 o;
  o.x = cvt_pk_bf16((v.x - mu) * rstd * gg.x + bb.x, (v.y - mu) * rstd * gg.y + bb.y);
  o.y = cvt_pk_bf16((v.z - mu) * rstd * gg.z + bb.z, (v.w - mu) * rstd * gg.w + bb.w);
  *(uint2*)&h[(size_t)row * DM + c] = o;
}

// ---------------- weight convert+transpose core ----------------
__device__ __forceinline__ void wtrans_body(const float* __restrict__ W,
                                            unsigned short* __restrict__ WT,
                                            int K, int N, int k0, int n0, int tid) {
  __shared__ float t[64][68];
#pragma unroll
  for (int i = 0; i < 4; ++i) {
    int chunk = i * 256 + tid;
    int r = chunk >> 4, c = (chunk & 15) << 2;
    float4 v = *(const float4*)&W[(size_t)(k0 + r) * N + n0 + c];
    t[r][c] = v.x; t[r][c + 1] = v.y; t[r][c + 2] = v.z; t[r][c + 3] = v.w;
  }
  __syncthreads();
#pragma unroll
  for (int i = 0; i < 4; ++i) {
    int chunk = i * 256 + tid;
    int n = chunk >> 4, c = (chunk & 15) << 2;
    uint2 o;
    o.x = cvt_pk_bf16(t[c][n], t[c + 1][n]);
    o.y = cvt_pk_bf16(t[c + 2][n], t[c + 3][n]);
    *(uint2*)&WT[(size_t)(n0 + n) * K + k0 + c] = o;
  }
}

// standalone (head)
__global__ __launch_bounds__(256) void k_wtrans(const float* __restrict__ W,
                                                unsigned short* __restrict__ WT,
                                                int K, int N) {
  wtrans_body(W, WT, K, N, blockIdx.x * 64, blockIdx.y * 64, threadIdx.x);
}

// all 4 per-layer weights in one launch (segmented block ranges)
__global__ __launch_bounds__(256) void k_wtrans4(const float* __restrict__ W0,
                                                 const float* __restrict__ W1,
                                                 const float* __restrict__ W2,
                                                 const float* __restrict__ W3,
                                                 unsigned short* __restrict__ T0,
                                                 unsigned short* __restrict__ T1,
                                                 unsigned short* __restrict__ T2,
                                                 unsigned short* __restrict__ T3) {
  int id = blockIdx.x;
  const float* W; unsigned short* WT; int K, N, lid;
  if (id < 768)       { W = W0; WT = T0; K = 1024; N = 3072; lid = id; }
  else if (id < 1024) { W = W1; WT = T1; K = 1024; N = 1024; lid = id - 768; }
  else if (id < 2048) { W = W2; WT = T2; K = 1024; N = 4096; lid = id - 1024; }
  else                { W = W3; WT = T3; K = 4096; N = 1024; lid = id - 2048; }
  int kb = K >> 6;
  wtrans_body(W, WT, K, N, (lid % kb) * 64, (lid / kb) * 64, threadIdx.x);
}

// ---------------- 128x128 GEMM, T3 2-phase prefetch ----------------
// EPI: 0=qkv scatter(+bias, Q pre-scaled by SCL, V transposed), 1=gelu->bf16, 2=bf16 partials
template <int EPI>
__global__ __launch_bounds__(256) void k_gemm(const unsigned short* __restrict__ A,
                                              const unsigned short* __restrict__ BT,
                                              const float* __restrict__ bias,
                                              unsigned short* __restrict__ part,
                                              unsigned short* __restrict__ outb,
                                              float* __restrict__ outf,
                                              int N, int K, int NT, int KS) {
  __shared__ unsigned short As[2][128 * 64];
  __shared__ unsigned short Bs[2][128 * 64];
  int tid = threadIdx.x;
  int wid = tid >> 6, lane = tid & 63;
  int lr = lane & 15, lg = lane >> 4;

  int id = xcd_swizzle(blockIdx.x, gridDim.x);
  int mt = id & 15;
  int rest = id >> 4;
  int nt = rest % NT;
  int ks = rest / NT;
  int m0 = mt * 128, n0 = nt * 128;
  int Kslice = K / KS;
  int kbeg = ks * Kslice;
  int nk = Kslice >> 6;

  int wm = (wid >> 1) * 64, wn = (wid & 1) * 64;

  fx4 acc[4][4] = {};

#define GSTAGE(buf, kt)                                                         \
  {                                                                             \
    _Pragma("unroll")                                                           \
    for (int i = 0; i < 4; ++i) {                                               \
      int chunk = i * 256 + tid;                                                \
      int r = chunk >> 3, slot = chunk & 7;                                     \
      int c = ((slot ^ (r & 7)) << 3);                                          \
      gload_lds16(&A[(size_t)(m0 + r) * K + (kt) + c], &As[buf][chunk << 3]);   \
      gload_lds16(&BT[(size_t)(n0 + r) * K + (kt) + c], &Bs[buf][chunk << 3]);  \
    }                                                                           \
  }

  GSTAGE(0, kbeg);
  for (int ik = 0; ik < nk; ++ik) {
    int cur = ik & 1;
    if (ik + 1 < nk) {
      GSTAGE(cur ^ 1, kbeg + (ik + 1) * 64);
      asm volatile("s_waitcnt vmcnt(8)" ::: "memory");   // oldest 8 = current tile
    } else {
      asm volatile("s_waitcnt vmcnt(0)" ::: "memory");
    }
    __builtin_amdgcn_sched_barrier(0);
    __builtin_amdgcn_s_barrier();                        // current tile visible to all
    __builtin_amdgcn_sched_barrier(0);
#pragma unroll
    for (int kk = 0; kk < 2; ++kk) {
      int slotz = (kk * 4 + lg) ^ (lr & 7);
      sx8 fa[4], fb[4];
#pragma unroll
      for (int mi = 0; mi < 4; ++mi)
        fa[mi] = *(const sx8*)&As[cur][(wm + mi * 16 + lr) * 64 + slotz * 8];
#pragma unroll
      for (int ni = 0; ni < 4; ++ni)
        fb[ni] = *(const sx8*)&Bs[cur][(wn + ni * 16 + lr) * 64 + slotz * 8];
#pragma unroll
      for (int mi = 0; mi < 4; ++mi)
#pragma unroll
        for (int ni = 0; ni < 4; ++ni)
          acc[mi][ni] = __builtin_amdgcn_mfma_f32_16x16x32_bf16(fb[ni], fa[mi], acc[mi][ni], 0, 0, 0);
    }
    asm volatile("s_waitcnt lgkmcnt(0)" ::: "memory");   // my ds_reads landed
    __builtin_amdgcn_sched_barrier(0);
    __builtin_amdgcn_s_barrier();                        // safe to overwrite cur next iter
  }
#undef GSTAGE

#pragma unroll
  for (int ni = 0; ni < 4; ++ni) {
    int col0 = n0 + wn + ni * 16 + lg * 4;
    float4 bv = {0.f, 0.f, 0.f, 0.f};
    if (bias && ks == 0) bv = *(const float4*)&bias[col0];
#pragma unroll
    for (int mi = 0; mi < 4; ++mi) {
      int row = m0 + wm + mi * 16 + lr;
      float v0 = acc[mi][ni][0] + bv.x;
      float v1 = acc[mi][ni][1] + bv.y;
      float v2 = acc[mi][ni][2] + bv.z;
      float v3 = acc[mi][ni][3] + bv.w;
      if constexpr (EPI == 0) {
        int bb = row >> 10, tt = row & 1023;
        if (col0 < 2048) {
          int which = col0 >> 10;
          if (which == 0) {  // pre-scale Q by 1/sqrt(d)*log2(e): (Q*s)@K == (Q@K)*s
            const float SCLQ = 0.125f * 1.44269504f;
            v0 *= SCLQ; v1 *= SCLQ; v2 *= SCLQ; v3 *= SCLQ;
          }
          int hc = col0 & 1023;
          uint2 o = {cvt_pk_bf16(v0, v1), cvt_pk_bf16(v2, v3)};
          *(uint2*)&outb[(size_t)which * NTOK * DM +
                         (((size_t)bb * NH + (hc >> 6)) * T_SEQ + tt) * DH + (hc & 63)] = o;
        } else {
          int dc = col0 - 2048;
          unsigned short* vt = outb + (size_t)2 * NTOK * DM;
          size_t base = (((size_t)bb * NH + (dc >> 6)) * DH + (dc & 63)) * T_SEQ + tt;
          vt[base] = f2bf(v0);
          vt[base + T_SEQ] = f2bf(v1);
          vt[base + 2 * T_SEQ] = f2bf(v2);
          vt[base + 3 * T_SEQ] = f2bf(v3);
        }
      } else if constexpr (EPI == 1) {
        float g0 = 0.5f * v0 * (1.0f + erff(v0 * 0.70710678f));
        float g1 = 0.5f * v1 * (1.0f + erff(v1 * 0.70710678f));
        float g2 = 0.5f * v2 * (1.0f + erff(v2 * 0.70710678f));
        float g3 = 0.5f * v3 * (1.0f + erff(v3 * 0.70710678f));
        uint2 o = {cvt_pk_bf16(g0, g1), cvt_pk_bf16(g2, g3)};
        *(uint2*)&outb[(size_t)row * N + col0] = o;
      } else {  // bf16 partial slice (split-K)
        uint2 o = {cvt_pk_bf16(v0, v1), cvt_pk_bf16(v2, v3)};
        *(uint2*)&part[((size_t)ks * NTOK + row) * DM + col0] = o;
      }
    }
  }
}

// ---------------- 256x256 8-phase GEMM (head) — R8 proven version ----------------
#define LDSUB(buf, ab, kk) (lds + (((buf) * 2 + (ab)) * 2 + (kk)) * 8192)

__device__ __forceinline__ void stage_half(const unsigned short* g, int rowstride,
                                           unsigned short* ldsbase, int tid, int k0) {
#pragma unroll
  for (int r = 0; r < 2; ++r) {
    int chunk = r * 512 + tid;
    int row = chunk >> 2, slot = chunk & 3;
    gload_lds16(g + (size_t)row * rowstride + k0 + ((slot ^ ((row >> 1) & 3)) << 3),
                ldsbase + (chunk << 3));
  }
}

__global__ __launch_bounds__(512, 2) void k_gemm256(const unsigned short* __restrict__ A,
                                                    const unsigned short* __restrict__ BT,
                                                    float* __restrict__ outf,
                                                    int N, int K) {
  __shared__ unsigned short lds[8 * 8192];   // 128 KB
  int tid = threadIdx.x;
  int wid = tid >> 6, lane = tid & 63;
  int lr = lane & 15, lg = lane >> 4;
  int wm2 = wid >> 2, wn4 = wid & 3;
  int id = xcd_swizzle(blockIdx.x, gridDim.x);
  int mt = id & 7, nt = id >> 3;          // mt fastest: 8 blocks share B panel
  int m0 = mt * 256, n0 = nt * 256;
  const unsigned short* Ab = A + (size_t)m0 * K;
  const unsigned short* Bb = BT + (size_t)n0 * K;
  int NIT = K >> 7;                        // 2 K-tiles (of 64) per iteration
  int swz = (lg ^ ((lr >> 1) & 3)) << 3;   // matches stage_half swizzle
  float* obase = outf + (size_t)(m0 + wm2 * 128 + lr) * N + n0 + wn4 * 64 + lg * 4;

  fx4 acc[8][4] = {};

  // prologue: tile0 {A0,B0,A1,B1}, tile1 {A0,B0,A1} = 7 half-tiles (14 loads)
  stage_half(Ab, K, LDSUB(0, 0, 0), tid, 0);
  stage_half(Bb, K, LDSUB(0, 1, 0), tid, 0);
  stage_half(Ab, K, LDSUB(0, 0, 1), tid, 32);
  stage_half(Bb, K, LDSUB(0, 1, 1), tid, 32);
  stage_half(Ab, K, LDSUB(1, 0, 0), tid, 64);
  stage_half(Bb, K, LDSUB(1, 1, 0), tid, 64);
  stage_half(Ab, K, LDSUB(1, 0, 1), tid, 96);
  asm volatile("s_waitcnt vmcnt(6)" ::: "memory");   // tile0 fully staged
  __builtin_amdgcn_s_barrier();

#define PHASE(BUF, KK, NHH, LOADA, STG, VMW)                                         \
  {                                                                                  \
    if (LOADA) {                                                                     \
      const unsigned short* sA = LDSUB(BUF, 0, KK);                                  \
      _Pragma("unroll")                                                              \
      for (int mi = 0; mi < 8; ++mi)                                                 \
        fa[mi] = *(const sx8*)&sA[(wm2 * 128 + mi * 16 + lr) * 32 + swz];            \
    }                                                                                \
    {                                                                                \
      const unsigned short* sB = LDSUB(BUF, 1, KK);                                  \
      _Pragma("unroll")                                                              \
      for (int j = 0; j < 2; ++j)                                                    \
        fb[j] = *(const sx8*)&sB[(wn4 * 64 + (NHH) * 32 + j * 16 + lr) * 32 + swz];  \
    }                                                                                \
    STG;                                                                             \
    VMW;                                                                             \
    __builtin_amdgcn_sched_barrier(0);                                               \
    __builtin_amdgcn_s_barrier();                                                    \
    asm volatile("s_waitcnt lgkmcnt(0)" ::: "memory");                               \
    __builtin_amdgcn_sched_barrier(0);                                               \
    __builtin_amdgcn_s_setprio(1);                                                   \
    _Pragma("unroll")                                                                \
    for (int mi = 0; mi < 8; ++mi) {                                                 \
      acc[mi][(NHH) * 2 + 0] = __builtin_amdgcn_mfma_f32_16x16x32_bf16(              \
          fb[0], fa[mi], acc[mi][(NHH) * 2 + 0], 0, 0, 0);                           \
      acc[mi][(NHH) * 2 + 1] = __builtin_amdgcn_mfma_f32_16x16x32_bf16(              \
          fb[1], fa[mi], acc[mi][(NHH) * 2 + 1], 0, 0, 0);                           \
    }                                                                                \
    __builtin_amdgcn_s_setprio(0);                                                   \
    __builtin_amdgcn_sched_barrier(0);                                               \
    __builtin_amdgcn_s_barrier();                                                    \
  }

  for (int it = 0; it < NIT; ++it) {
    bool st = (it < NIT - 1);
    bool last = (it == NIT - 1);
    int t1k = (2 * it + 1) * 64;
    int t2k = (2 * it + 2) * 64;
    int t3k = (2 * it + 3) * 64;
    sx8 fa[8], fb[2];

    PHASE(0, 0, 0, true,
          { stage_half(Bb, K, LDSUB(1, 1, 1), tid, t1k + 32); }, {});
    PHASE(0, 0, 1, false,
          { if (st) stage_half(Ab, K, LDSUB(0, 0, 0), tid, t2k); }, {});
    PHASE(0, 1, 0, true,
          { if (st) stage_half(Bb, K, LDSUB(0, 1, 0), tid, t2k); }, {});
    PHASE(0, 1, 1, false,
          { if (st) stage_half(Ab, K, LDSUB(0, 0, 1), tid, t2k + 32); },
          { if (last) { asm volatile("s_waitcnt vmcnt(0)" ::: "memory"); }
            else      { asm volatile("s_waitcnt vmcnt(6)" ::: "memory"); } });
    PHASE(1, 0, 0, true,
          { if (st) stage_half(Bb, K, LDSUB(0, 1, 1), tid, t2k + 32); }, {});
    PHASE(1, 0, 1, false,
          { if (st) stage_half(Ab, K, LDSUB(1, 0, 0), tid, t3k); }, {});
    PHASE(1, 1, 0, true,
          { if (st) stage_half(Bb, K, LDSUB(1, 1, 0), tid, t3k); }, {});
    // split epilogue: nj 0,1 final after p7 -> store overlapped with p8
    if (last) {
#pragma unroll
      for (int mi = 0; mi < 8; ++mi) {
        *(float4*)(obase + (size_t)mi * 16 * N) =
            (float4){acc[mi][0][0], acc[mi][0][1], acc[mi][0][2], acc[mi][0][3]};
        *(float4*)(obase + (size_t)mi * 16 * N + 16) =
            (float4){acc[mi][1][0], acc[mi][1][1], acc[mi][1][2], acc[mi][1][3]};
      }
    }
    PHASE(1, 1, 1, false,
          { if (st) stage_half(Ab, K, LDSUB(1, 0, 1), tid, t3k + 32); },
          { if (!last) { asm volatile("s_waitcnt vmcnt(6)" ::: "memory"); } });
  }
#undef PHASE

  // remaining quadrants nj 2,3
#pragma unroll
  for (int mi = 0; mi < 8; ++mi) {
    *(float4*)(obase + (size_t)mi * 16 * N + 32) =
        (float4){acc[mi][2][0], acc[mi][2][1], acc[mi][2][2], acc[mi][2][3]};
    *(float4*)(obase + (size_t)mi * 16 * N + 48) =
        (float4){acc[mi][3][0], acc[mi][3][1], acc[mi][3][2], acc[mi][3][3]};
  }
}

// ---------------- flash attention, KVBLK=128, pipelined staging, MFMA row-sum ----------------
__global__ __launch_bounds__(256) void k_attn(const unsigned short* __restrict__ gq,
                                              const unsigned short* __restrict__ gk,
                                              const unsigned short* __restrict__ gvt,
                                              unsigned short* __restrict__ y) {
  __shared__ unsigned short Ks[128 * 64];
  __shared__ unsigned short Vt[64 * 128];
  __shared__ unsigned short Pw[4][16 * 136];
  int id = xcd_swizzle(blockIdx.x, gridDim.x);
  int bh = id >> 4, qt = 15 - (id & 15);
  int tid = threadIdx.x, wid = tid >> 6, lane = tid & 63;
  int lr = lane & 15, lg = lane >> 4;
  int q0 = qt * 64 + wid * 16;
  int qg = q0 + lr;

#define STAGE_K(kt0)                                                                  \
  {                                                                                   \
    _Pragma("unroll")                                                                 \
    for (int i = 0; i < 4; ++i) {                                                     \
      int chunk = i * 256 + tid;                                                      \
      int r = chunk >> 3, s = chunk & 7;                                              \
      gload_lds16(&gk[((size_t)bh * T_SEQ + (kt0) + r) * DH + ((s ^ (r & 7)) << 3)],  \
                  &Ks[chunk << 3]);                                                   \
    }                                                                                 \
  }
#define STAGE_V(kt0)                                                                  \
  {                                                                                   \
    _Pragma("unroll")                                                                 \
    for (int i = 0; i < 4; ++i) {                                                     \
      int chunk = i * 256 + tid;                                                      \
      int r = chunk >> 4, s = chunk & 15;                                             \
      gload_lds16(&gvt[((size_t)bh * DH + r) * T_SEQ + (kt0) + ((s ^ (r & 15)) << 3)],\
                  &Vt[chunk << 3]);                                                   \
    }                                                                                 \
  }

  sx8 qf[2];
  {
    const unsigned short* qp = gq + ((size_t)bh * T_SEQ + qg) * DH + lg * 8;
    qf[0] = *(const sx8*)qp;
    qf[1] = *(const sx8*)(qp + 32);
  }
  sx8 ones;   // bf16 1.0 frag for MFMA row-sum
#pragma unroll
  for (int i = 0; i < 8; ++i) ones[i] = (short)0x3F80;

  fx4 yacc[4] = {};
  fx4 sacc = {};                      // running sum(P) per q-row (MFMA ones-trick)
  float mrun = -1e30f;                // lane-local (q-row = lr), log2 domain

  // prologue: K(0) then V(0); wait K only (V drains at first tile's vmcnt(0))
  STAGE_K(0);
  STAGE_V(0);
  asm volatile("s_waitcnt vmcnt(4)" ::: "memory");
  __builtin_amdgcn_sched_barrier(0);
  __builtin_amdgcn_s_barrier();

  int jmax = qt >> 1;
  for (int j = 0; j <= jmax; ++j) {
    int kt0 = j * 128;
    bool more = (j < jmax);

    // S^T = K Q^T (Q pre-scaled at qkv epilogue -> st already in log2 domain)
    fx4 st[8] = {};
#pragma unroll
    for (int kk = 0; kk < 2; ++kk) {
      int slotz = (kk * 4 + lg) ^ (lr & 7);
#pragma unroll
      for (int mi = 0; mi < 8; ++mi) {
        sx8 kb = *(const sx8*)&Ks[(mi * 16 + lr) * 64 + slotz * 8];
        st[mi] = __builtin_amdgcn_mfma_f32_16x16x32_bf16(kb, qf[kk], st[mi], 0, 0, 0);
      }
    }

    float pvv[8][4];
    float pmax = -1e30f;
    if (j < jmax) {   // bulk tiles: no causal mask
#pragma unroll
      for (int mi = 0; mi < 8; ++mi)
#pragma unroll
        for (int rg = 0; rg < 4; ++rg) {
          float val = st[mi][rg];
          pvv[mi][rg] = val;
          pmax = fmaxf(pmax, val);
        }
    } else {          // final tile: causal mask
#pragma unroll
      for (int mi = 0; mi < 8; ++mi)
#pragma unroll
        for (int rg = 0; rg < 4; ++rg) {
          float val = st[mi][rg];
          if ((kt0 + mi * 16 + lg * 4 + rg) > qg) val = -1e30f;
          pvv[mi][rg] = val;
          pmax = fmaxf(pmax, val);
        }
    }
    pmax = fmaxf(pmax, __shfl_xor(pmax, 16));
    pmax = fmaxf(pmax, __shfl_xor(pmax, 32));
    // defer-max (T13): rescale only when max grew > 11.5 (= e^8 in log2 units)
    if (!__all(pmax <= mrun + 11.5f)) {
      float mnew = fmaxf(mrun, pmax);
      float sc = exp2f(mrun - mnew);
#pragma unroll
      for (int rg = 0; rg < 4; ++rg) sacc[rg] *= sc;
#pragma unroll
      for (int dt = 0; dt < 4; ++dt)
#pragma unroll
        for (int rg = 0; rg < 4; ++rg) yacc[dt][rg] *= sc;
      mrun = mnew;
    }
#pragma unroll
    for (int mi = 0; mi < 8; ++mi)
#pragma unroll
      for (int rg = 0; rg < 4; ++rg)
        pvv[mi][rg] = exp2f(pvv[mi][rg] - mrun);

    // P -> per-wave LDS: uint2 (b64) writes, HW cvt_pk
#pragma unroll
    for (int mi = 0; mi < 8; ++mi) {
      uint2 pk2 = {cvt_pk_bf16(pvv[mi][0], pvv[mi][1]),
                   cvt_pk_bf16(pvv[mi][2], pvv[mi][3])};
      *(uint2*)&Pw[wid][lr * 136 + mi * 16 + lg * 4] = pk2;
    }

    // V(j) landed + all waves' Ks reads complete
    asm volatile("s_waitcnt vmcnt(0)" ::: "memory");
    __builtin_amdgcn_sched_barrier(0);
    __builtin_amdgcn_s_barrier();
    __builtin_amdgcn_sched_barrier(0);

    // stage next K into Ks while PV computes (Ks free after barrier above)
    if (more) STAGE_K(kt0 + 128);

    // PV + MFMA row-sum (ones-frag): sacc[rg] accumulates sum_k P for q=lr
#pragma unroll
    for (int kk = 0; kk < 4; ++kk) {
      sx8 pa = *(const sx8*)&Pw[wid][lr * 136 + kk * 32 + lg * 8];
      int slotz = (kk * 4 + lg) ^ lr;
#pragma unroll
      for (int dt = 0; dt < 4; ++dt) {
        sx8 vb = *(const sx8*)&Vt[(dt * 16 + lr) * 128 + slotz * 8];
        yacc[dt] = __builtin_amdgcn_mfma_f32_16x16x32_bf16(vb, pa, yacc[dt], 0, 0, 0);
      }
      sacc = __builtin_amdgcn_mfma_f32_16x16x32_bf16(ones, pa, sacc, 0, 0, 0);
    }

    if (more) {
      // all waves done reading Vt -> stage next V; then confirm K(j+1) landed
      asm volatile("s_waitcnt lgkmcnt(0)" ::: "memory");
      __builtin_amdgcn_sched_barrier(0);
      __builtin_amdgcn_s_barrier();
      __builtin_amdgcn_sched_barrier(0);
      STAGE_V(kt0 + 128);
      asm volatile("s_waitcnt vmcnt(4)" ::: "memory");   // 4 newest (V) stay in flight
      __builtin_amdgcn_sched_barrier(0);
      __builtin_amdgcn_s_barrier();
    }
  }
#undef STAGE_K
#undef STAGE_V

  float inv = 1.0f / sacc[0];
  int tok = (bh >> 4) * T_SEQ + qg;
  int colbase = (bh & 15) * DH;
#pragma unroll
  for (int dt = 0; dt < 4; ++dt) {
    uint2 o;
    o.x = cvt_pk_bf16(yacc[dt][0] * inv, yacc[dt][1] * inv);
    o.y = cvt_pk_bf16(yacc[dt][2] * inv, yacc[dt][3] * inv);
    *(uint2*)&y[(size_t)tok * DM + colbase + dt * 16 + lg * 4] = o;
  }
}

// ---------------- launcher ----------------
extern "C" void kernel_launch(void* const* d_in, const int* in_sizes, int n_in,
                              void* d_out, int out_size, void* d_ws, size_t ws_size,
                              hipStream_t stream) {
  (void)in_sizes; (void)n_in; (void)out_size; (void)ws_size;
  const int*   idx     = (const int*)d_in[0];
  const float* tok_emb = (const float*)d_in[1];
  const float* pos_emb = (const float*)d_in[2];
  const float* ln1_s   = (const float*)d_in[3];
  const float* ln1_b   = (const float*)d_in[4];
  const float* qkv_w   = (const float*)d_in[5];
  const float* qkv_b   = (const float*)d_in[6];
  const float* out_w   = (const float*)d_in[7];
  const float* out_b   = (const float*)d_in[8];
  const float* ln2_s   = (const float*)d_in[9];
  const float* ln2_b   = (const float*)d_in[10];
  const float* mlp_w1  = (const float*)d_in[11];
  const float* mlp_b1  = (const float*)d_in[12];
  const float* mlp_w2  = (const float*)d_in[13];
  const float* mlp_b2  = (const float*)d_in[14];
  const float* lnf_s   = (const float*)d_in[15];
  const float* lnf_b   = (const float*)d_in[16];
  const float* head_w  = (const float*)d_in[17];

  char* p = (char*)d_ws;
  float* x          = (float*)p;          p += (size_t)NTOK * DM * 4;
  unsigned short* h = (unsigned short*)p; p += (size_t)NTOK * DM * 2;
  unsigned short* qkvb = (unsigned short*)p; p += (size_t)3 * NTOK * DM * 2;
  unsigned short* yb = (unsigned short*)p; p += (size_t)NTOK * DM * 2;
  unsigned short* m1 = (unsigned short*)p; p += (size_t)NTOK * DFF * 2;
  unsigned short* wt = (unsigned short*)p;                         // 64 MB (head)
  unsigned short* wtq  = wt;                                       // 3M elems
  unsigned short* wto  = wt + (size_t)3 * 1024 * 1024;             // 1M
  unsigned short* wtm1 = wt + (size_t)4 * 1024 * 1024;             // 4M
  unsigned short* wtm2 = wt + (size_t)8 * 1024 * 1024;             // 4M (24 MB total)
  unsigned short* part = (unsigned short*)(p + 32 * 1024 * 1024);  // bf16 partials

  dim3 blk(256);

  k_embed_ln<<<NTOK, blk, 0, stream>>>(idx, tok_emb, pos_emb, ln1_s, ln1_b, x, h);

  for (int l = 0; l < NL; ++l) {
    k_wtrans4<<<3072, blk, 0, stream>>>(qkv_w + (size_t)l * DM * 3 * DM,
                                        out_w + (size_t)l * DM * DM,
                                        mlp_w1 + (size_t)l * DM * DFF,
                                        mlp_w2 + (size_t)l * DFF * DM,
                                        wtq, wto, wtm1, wtm2);
    k_gemm<0><<<16 * 24, blk, 0, stream>>>(h, wtq, qkv_b + l * 3 * DM,
                                           nullptr, qkvb, nullptr, 3 * DM, DM, 24, 1);
    k_attn<<<512, blk, 0, stream>>>(qkvb, qkvb + (size_t)NTOK * DM,
                                    qkvb + (size_t)2 * NTOK * DM, yb);
    k_gemm<2><<<16 * 8 * 4, blk, 0, stream>>>(yb, wto, out_b + l * DM,
                                              part, nullptr, nullptr, DM, DM, 8, 4);
    k_reduce_ln<<<NTOK, blk, 0, stream>>>(part, x, ln2_s + l * DM, ln2_b + l * DM, h);
    k_gemm<1><<<16 * 32, blk, 0, stream>>>(h, wtm1, mlp_b1 + l * DFF,
                                           nullptr, m1, nullptr, DFF, DM, 32, 1);
    k_gemm<2><<<16 * 8 * 4, blk, 0, stream>>>(m1, wtm2, mlp_b2 + l * DM,
                                              part, nullptr, nullptr, DM, DFF, 8, 4);
    if (l < NL - 1)
      k_reduce_ln<<<NTOK, blk, 0, stream>>>(part, x, ln1_s + (l + 1) * DM, ln1_b + (l + 1) * DM, h);
    else
      k_reduce_ln<<<NTOK, blk, 0, stream>>>(part, x, lnf_s, lnf_b, h);
  }

  k_wtrans<<<dim3(DM / 64, VOCAB / 64), blk, 0, stream>>>(head_w, wt, DM, VOCAB);
  k_gemm256<<<1000, 512, 0, stream>>>(h, wt, (float*)d_out, VOCAB, DM);
}

// Round 13
// 1087.414 us; speedup vs baseline: 1.1965x; 1.0007x over previous
//
#include <hip/hip_runtime.h>

// GPT2-like forward, MI355X. Round 12:
// - softmax diet: (1) QK scale folded into Q at qkv epilogue, (2) P row-sum via
//   MFMA ones-trick (replaces 32 fadd + 2 shfl), (3) uint2 P-writes (8 ds_write_b64)
// - everything else identical to R11 (head 8-phase, 2-phase layer GEMMs, pipelined attn staging)

#define T_SEQ 1024
#define NTOK  2048   // B*T
#define DM    1024
#define DFF   4096
#define NH    16
#define DH    64
#define NL    6
#define VOCAB 32000

typedef short sx8 __attribute__((ext_vector_type(8)));          // 8 bf16 (4 VGPR) MFMA frag
typedef float fx4 __attribute__((ext_vector_type(4)));          // MFMA acc
typedef unsigned short usx4 __attribute__((ext_vector_type(4)));
typedef unsigned int   uix4 __attribute__((ext_vector_type(4))); // 16B copy

__device__ __forceinline__ unsigned short f2bf(float f) {
  union { float f; unsigned u; } c; c.f = f;
  unsigned r = c.u + 0x7FFFu + ((c.u >> 16) & 1u);   // round-nearest-even
  return (unsigned short)(r >> 16);
}
__device__ __forceinline__ float bf2f(unsigned short u) {
  union { unsigned u; float f; } c; c.u = ((unsigned)u) << 16;
  return c.f;
}
// HW packed f32->2xbf16 convert (no builtin on gfx950; T12 primitive)
__device__ __forceinline__ unsigned cvt_pk_bf16(float lo, float hi) {
  unsigned r;
  asm("v_cvt_pk_bf16_f32 %0, %1, %2" : "=v"(r) : "v"(lo), "v"(hi));
  return r;
}

__device__ __forceinline__ void gload_lds16(const unsigned short* g, unsigned short* l) {
  __builtin_amdgcn_global_load_lds(
      (const __attribute__((address_space(1))) unsigned int*)g,
      (__attribute__((address_space(3))) unsigned int*)l, 16, 0, 0);
}

// bijective XCD-chunked swizzle (m204)
__device__ __forceinline__ int xcd_swizzle(int orig, int nwg) {
  int q = nwg >> 3, r = nwg & 7;
  int xcd = orig & 7, idx = orig >> 3;
  int base = (xcd < r) ? xcd * (q + 1) : r * (q + 1) + (xcd - r) * q;
  return base + idx;
}

// ---------------- fused embedding + ln1(layer0) ----------------
__global__ __launch_bounds__(256) void k_embed_ln(const int* __restrict__ idx,
                                                  const float* __restrict__ tok,
                                                  const float* __restrict__ pos,
                                                  const float* __restrict__ g,
                                                  const float* __restrict__ b,
                                                  float* __restrict__ x,
                                                  unsigned short* __restrict__ h) {
  int token = blockIdx.x;
  int t = token & (T_SEQ - 1);
  int id = idx[token];
  int tid = threadIdx.x;
  int c = tid * 4;
  float4 tv = *(const float4*)&tok[(size_t)id * DM + c];
  float4 pv = *(const float4*)&pos[(size_t)t * DM + c];
  float4 v;
  v.x = tv.x + pv.x; v.y = tv.y + pv.y; v.z = tv.z + pv.z; v.w = tv.w + pv.w;
  *(float4*)&x[(size_t)token * DM + c] = v;
  float s = v.x + v.y + v.z + v.w;
  float q = v.x * v.x + v.y * v.y + v.z * v.z + v.w * v.w;
  for (int off = 32; off > 0; off >>= 1) {
    s += __shfl_down(s, off);
    q += __shfl_down(q, off);
  }
  __shared__ float red[8];
  int wid = tid >> 6, lane = tid & 63;
  if (lane == 0) { red[wid] = s; red[4 + wid] = q; }
  __syncthreads();
  s = red[0] + red[1] + red[2] + red[3];
  q = red[4] + red[5] + red[6] + red[7];
  float mu = s * (1.0f / DM);
  float var = q * (1.0f / DM) - mu * mu;
  float rstd = rsqrtf(var + 1e-5f);
  float4 gg = *(const float4*)&g[c];
  float4 bb = *(const float4*)&b[c];
  uint2 o;
  o.x = cvt_pk_bf16((v.x - mu) * rstd * gg.x + bb.x, (v.y - mu) * rstd * gg.y + bb.y);
  o.y = cvt_pk_bf16((v.z - mu) * rstd * gg.z + bb.z, (v.w - mu) * rstd * gg.w + bb.w);
  *(uint2*)&h[(size_t)token * DM + c] = o;
}

// ------------- fused split-K(4) reduce (bf16 partials) + residual + layernorm -------------
__global__ __launch_bounds__(256) void k_reduce_ln(const unsigned short* __restrict__ part,
                                                   float* __restrict__ x,
                                                   const float* __restrict__ g,
                                                   const float* __restrict__ b,
                                                   unsigned short* __restrict__ h) {
  int row = blockIdx.x;
  int tid = threadIdx.x;
  int c = tid * 4;
  float4 v = *(const float4*)&x[(size_t)row * DM + c];
#pragma unroll
  for (int s4 = 0; s4 < 4; ++s4) {
    usx4 p = *(const usx4*)&part[((size_t)s4 * NTOK + row) * DM + c];
    v.x += bf2f(p[0]); v.y += bf2f(p[1]); v.z += bf2f(p[2]); v.w += bf2f(p[3]);
  }
  *(float4*)&x[(size_t)row * DM + c] = v;
  float s = v.x + v.y + v.z + v.w;
  float q = v.x * v.x + v.y * v.y + v.z * v.z + v.w * v.w;
  for (int off = 32; off > 0; off >>= 1) {
    s += __shfl_down(s, off);
    q += __shfl_down(q, off);
  }
  __shared__ float red[8];
  int wid = tid >> 6, lane = tid & 63;
  if (lane == 0) { red[wid] = s; red[4 + wid] = q; }
  __syncthreads();
  s = red[0] + red[1] + red[2] + red[3];
  q = red[4] + red[5] + red[6] + red[7];
  float mu = s * (1.0f / DM);
  float var = q * (1.0f / DM) - mu * mu;
  float rstd = rsqrtf(var + 1e-5f);
  float4 gg = *(const float4*)&g[c];
  float4 bb = *(const float4*)&b[c];
  uint2 o;
  o.x = cvt_pk_bf16((v.x - mu) * rstd * gg.x + bb.x, (v.y - mu) * rstd * gg.y + bb.y);
  o.y = cvt_pk_bf16((v.z - mu) * rstd * gg.z + bb.z, (v.w - mu) * rstd * gg.w + bb.w);
  *(uint2*)&h[(size_t)row * DM + c] = o;
}

// ---------------- weight convert+transpose core ----------------
__device__ __forceinline__ void wtrans_body(const float* __restrict__ W,
                                            unsigned short* __restrict__ WT,
                                            int K, int N, int k0, int n0, int tid) {
  __shared__ float t[64][68];
#pragma unroll
  for (int i = 0; i < 4; ++i) {
    int chunk = i * 256 + tid;
    int r = chunk >> 4, c = (chunk & 15) << 2;
    float4 v = *(const float4*)&W[(size_t)(k0 + r) * N + n0 + c];
    t[r][c] = v.x; t[r][c + 1] = v.y; t[r][c + 2] = v.z; t[r][c + 3] = v.w;
  }
  __syncthreads();
#pragma unroll
  for (int i = 0; i < 4; ++i) {
    int chunk = i * 256 + tid;
    int n = chunk >> 4, c = (chunk & 15) << 2;
    uint2 o;
    o.x = cvt_pk_bf16(t[c][n], t[c + 1][n]);
    o.y = cvt_pk_bf16(t[c + 2][n], t[c + 3][n]);
    *(uint2*)&WT[(size_t)(n0 + n) * K + k0 + c] = o;
  }
}

// standalone (head)
__global__ __launch_bounds__(256) void k_wtrans(const float* __restrict__ W,
                                                unsigned short* __restrict__ WT,
                                                int K, int N) {
  wtrans_body(W, WT, K, N, blockIdx.x * 64, blockIdx.y * 64, threadIdx.x);
}

// all 4 per-layer weights in one launch (segmented block ranges)
__global__ __launch_bounds__(256) void k_wtrans4(const float* __restrict__ W0,
                                                 const float* __restrict__ W1,
                                                 const float* __restrict__ W2,
                                                 const float* __restrict__ W3,
                                                 unsigned short* __restrict__ T0,
                                                 unsigned short* __restrict__ T1,
                                                 unsigned short* __restrict__ T2,
                                                 unsigned short* __restrict__ T3) {
  int id = blockIdx.x;
  const float* W; unsigned short* WT; int K, N, lid;
  if (id < 768)       { W = W0; WT = T0; K = 1024; N = 3072; lid = id; }
  else if (id < 1024) { W = W1; WT = T1; K = 1024; N = 1024; lid = id - 768; }
  else if (id < 2048) { W = W2; WT = T2; K = 1024; N = 4096; lid = id - 1024; }
  else                { W = W3; WT = T3; K = 4096; N = 1024; lid = id - 2048; }
  int kb = K >> 6;
  wtrans_body(W, WT, K, N, (lid % kb) * 64, (lid / kb) * 64, threadIdx.x);
}

// ---------------- 128x128 GEMM, T3 2-phase prefetch ----------------
// EPI: 0=qkv scatter(+bias, Q pre-scaled by SCL, V transposed), 1=gelu->bf16, 2=bf16 partials
template <int EPI>
__global__ __launch_bounds__(256) void k_gemm(const unsigned short* __restrict__ A,
                                              const unsigned short* __restrict__ BT,
                                              const float* __restrict__ bias,
                                              unsigned short* __restrict__ part,
                                              unsigned short* __restrict__ outb,
                                              float* __restrict__ outf,
                                              int N, int K, int NT, int KS) {
  __shared__ unsigned short As[2][128 * 64];
  __shared__ unsigned short Bs[2][128 * 64];
  int tid = threadIdx.x;
  int wid = tid >> 6, lane = tid & 63;
  int lr = lane & 15, lg = lane >> 4;

  int id = xcd_swizzle(blockIdx.x, gridDim.x);
  int mt = id & 15;
  int rest = id >> 4;
  int nt = rest % NT;
  int ks = rest / NT;
  int m0 = mt * 128, n0 = nt * 128;
  int Kslice = K / KS;
  int kbeg = ks * Kslice;
  int nk = Kslice >> 6;

  int wm = (wid >> 1) * 64, wn = (wid & 1) * 64;

  fx4 acc[4][4] = {};

#define GSTAGE(buf, kt)                                                         \
  {                                                                             \
    _Pragma("unroll")                                                           \
    for (int i = 0; i < 4; ++i) {                                               \
      int chunk = i * 256 + tid;                                                \
      int r = chunk >> 3, slot = chunk & 7;                                     \
      int c = ((slot ^ (r & 7)) << 3);                                          \
      gload_lds16(&A[(size_t)(m0 + r) * K + (kt) + c], &As[buf][chunk << 3]);   \
      gload_lds16(&BT[(size_t)(n0 + r) * K + (kt) + c], &Bs[buf][chunk << 3]);  \
    }                                                                           \
  }

  GSTAGE(0, kbeg);
  for (int ik = 0; ik < nk; ++ik) {
    int cur = ik & 1;
    if (ik + 1 < nk) {
      GSTAGE(cur ^ 1, kbeg + (ik + 1) * 64);
      asm volatile("s_waitcnt vmcnt(8)" ::: "memory");   // oldest 8 = current tile
    } else {
      asm volatile("s_waitcnt vmcnt(0)" ::: "memory");
    }
    __builtin_amdgcn_sched_barrier(0);
    __builtin_amdgcn_s_barrier();                        // current tile visible to all
    __builtin_amdgcn_sched_barrier(0);
#pragma unroll
    for (int kk = 0; kk < 2; ++kk) {
      int slotz = (kk * 4 + lg) ^ (lr & 7);
      sx8 fa[4], fb[4];
#pragma unroll
      for (int mi = 0; mi < 4; ++mi)
        fa[mi] = *(const sx8*)&As[cur][(wm + mi * 16 + lr) * 64 + slotz * 8];
#pragma unroll
      for (int ni = 0; ni < 4; ++ni)
        fb[ni] = *(const sx8*)&Bs[cur][(wn + ni * 16 + lr) * 64 + slotz * 8];
#pragma unroll
      for (int mi = 0; mi < 4; ++mi)
#pragma unroll
        for (int ni = 0; ni < 4; ++ni)
          acc[mi][ni] = __builtin_amdgcn_mfma_f32_16x16x32_bf16(fb[ni], fa[mi], acc[mi][ni], 0, 0, 0);
    }
    asm volatile("s_waitcnt lgkmcnt(0)" ::: "memory");   // my ds_reads landed
    __builtin_amdgcn_sched_barrier(0);
    __builtin_amdgcn_s_barrier();                        // safe to overwrite cur next iter
  }
#undef GSTAGE

#pragma unroll
  for (int ni = 0; ni < 4; ++ni) {
    int col0 = n0 + wn + ni * 16 + lg * 4;
    float4 bv = {0.f, 0.f, 0.f, 0.f};
    if (bias && ks == 0) bv = *(const float4*)&bias[col0];
#pragma unroll
    for (int mi = 0; mi < 4; ++mi) {
      int row = m0 + wm + mi * 16 + lr;
      float v0 = acc[mi][ni][0] + bv.x;
      float v1 = acc[mi][ni][1] + bv.y;
      float v2 = acc[mi][ni][2] + bv.z;
      float v3 = acc[mi][ni][3] + bv.w;
      if constexpr (EPI == 0) {
        int bb = row >> 10, tt = row & 1023;
        if (col0 < 2048) {
          int which = col0 >> 10;
          if (which == 0) {  // pre-scale Q by 1/sqrt(d)*log2(e): (Q*s)@K == (Q@K)*s
            const float SCLQ = 0.125f * 1.44269504f;
            v0 *= SCLQ; v1 *= SCLQ; v2 *= SCLQ; v3 *= SCLQ;
          }
          int hc = col0 & 1023;
          uint2 o = {cvt_pk_bf16(v0, v1), cvt_pk_bf16(v2, v3)};
          *(uint2*)&outb[(size_t)which * NTOK * DM +
                         (((size_t)bb * NH + (hc >> 6)) * T_SEQ + tt) * DH + (hc & 63)] = o;
        } else {
          int dc = col0 - 2048;
          unsigned short* vt = outb + (size_t)2 * NTOK * DM;
          size_t base = (((size_t)bb * NH + (dc >> 6)) * DH + (dc & 63)) * T_SEQ + tt;
          vt[base] = f2bf(v0);
          vt[base + T_SEQ] = f2bf(v1);
          vt[base + 2 * T_SEQ] = f2bf(v2);
          vt[base + 3 * T_SEQ] = f2bf(v3);
        }
      } else if constexpr (EPI == 1) {
        float g0 = 0.5f * v0 * (1.0f + erff(v0 * 0.70710678f));
        float g1 = 0.5f * v1 * (1.0f + erff(v1 * 0.70710678f));
        float g2 = 0.5f * v2 * (1.0f + erff(v2 * 0.70710678f));
        float g3 = 0.5f * v3 * (1.0f + erff(v3 * 0.70710678f));
        uint2 o = {cvt_pk_bf16(g0, g1), cvt_pk_bf16(g2, g3)};
        *(uint2*)&outb[(size_t)row * N + col0] = o;
      } else {  // bf16 partial slice (split-K)
        uint2 o = {cvt_pk_bf16(v0, v1), cvt_pk_bf16(v2, v3)};
        *(uint2*)&part[((size_t)ks * NTOK + row) * DM + col0] = o;
      }
    }
  }
}

// ---------------- 256x256 8-phase GEMM (head) — R8 proven version ----------------
#define LDSUB(buf, ab, kk) (lds + (((buf) * 2 + (ab)) * 2 + (kk)) * 8192)

__device__ __forceinline__ void stage_half(const unsigned short* g, int rowstride,
                                           unsigned short* ldsbase, int tid, int k0) {
#pragma unroll
  for (int r = 0; r < 2; ++r) {
    int chunk = r * 512 + tid;
    int row = chunk >> 2, slot = chunk & 3;
    gload_lds16(g + (size_t)row * rowstride + k0 + ((slot ^ ((row >> 1) & 3)) << 3),
                ldsbase + (chunk << 3));
  }
}

__global__ __launch_bounds__(512, 2) void k_gemm256(const unsigned short* __restrict__ A,
                                                    const unsigned short* __restrict__ BT,
                                                    float* __restrict__ outf,
                                                    int N, int K) {
  __shared__ unsigned short lds[8 * 8192];   // 128 KB
  int tid = threadIdx.x;
  int wid = tid >> 6, lane = tid & 63;
  int lr = lane & 15, lg = lane >> 4;
  int wm2 = wid >> 2, wn4 = wid & 3;
  int id = xcd_swizzle(blockIdx.x, gridDim.x);
  int mt = id & 7, nt = id >> 3;          // mt fastest: 8 blocks share B panel
  int m0 = mt * 256, n0 = nt * 256;
  const unsigned short* Ab = A + (size_t)m0 * K;
  const unsigned short* Bb = BT + (size_t)n0 * K;
  int NIT = K >> 7;                        // 2 K-tiles (of 64) per iteration
  int swz = (lg ^ ((lr >> 1) & 3)) << 3;   // matches stage_half swizzle
  float* obase = outf + (size_t)(m0 + wm2 * 128 + lr) * N + n0 + wn4 * 64 + lg * 4;

  fx4 acc[8][4] = {};

  // prologue: tile0 {A0,B0,A1,B1}, tile1 {A0,B0,A1} = 7 half-tiles (14 loads)
  stage_half(Ab, K, LDSUB(0, 0, 0), tid, 0);
  stage_half(Bb, K, LDSUB(0, 1, 0), tid, 0);
  stage_half(Ab, K, LDSUB(0, 0, 1), tid, 32);
  stage_half(Bb, K, LDSUB(0, 1, 1), tid, 32);
  stage_half(Ab, K, LDSUB(1, 0, 0), tid, 64);
  stage_half(Bb, K, LDSUB(1, 1, 0), tid, 64);
  stage_half(Ab, K, LDSUB(1, 0, 1), tid, 96);
  asm volatile("s_waitcnt vmcnt(6)" ::: "memory");   // tile0 fully staged
  __builtin_amdgcn_s_barrier();

#define PHASE(BUF, KK, NHH, LOADA, STG, VMW)                                         \
  {                                                                                  \
    if (LOADA) {                                                                     \
      const unsigned short* sA = LDSUB(BUF, 0, KK);                                  \
      _Pragma("unroll")                                                              \
      for (int mi = 0; mi < 8; ++mi)                                                 \
        fa[mi] = *(const sx8*)&sA[(wm2 * 128 + mi * 16 + lr) * 32 + swz];            \
    }                                                                                \
    {                                                                                \
      const unsigned short* sB = LDSUB(BUF, 1, KK);                                  \
      _Pragma("unroll")                                                              \
      for (int j = 0; j < 2; ++j)                                                    \
        fb[j] = *(const sx8*)&sB[(wn4 * 64 + (NHH) * 32 + j * 16 + lr) * 32 + swz];  \
    }                                                                                \
    STG;                                                                             \
    VMW;                                                                             \
    __builtin_amdgcn_sched_barrier(0);                                               \
    __builtin_amdgcn_s_barrier();                                                    \
    asm volatile("s_waitcnt lgkmcnt(0)" ::: "memory");                               \
    __builtin_amdgcn_sched_barrier(0);                                               \
    __builtin_amdgcn_s_setprio(1);                                                   \
    _Pragma("unroll")                                                                \
    for (int mi = 0; mi < 8; ++mi) {                                                 \
      acc[mi][(NHH) * 2 + 0] = __builtin_amdgcn_mfma_f32_16x16x32_bf16(              \
          fb[0], fa[mi], acc[mi][(NHH) * 2 + 0], 0, 0, 0);                           \
      acc[mi][(NHH) * 2 + 1] = __builtin_amdgcn_mfma_f32_16x16x32_bf16(              \
          fb[1], fa[mi], acc[mi][(NHH) * 2 + 1], 0, 0, 0);                           \
    }                                                                                \
    __builtin_amdgcn_s_setprio(0);                                                   \
    __builtin_amdgcn_sched_barrier(0);                                               \
    __builtin_amdgcn_s_barrier();                                                    \
  }

  for (int it = 0; it < NIT; ++it) {
    bool st = (it < NIT - 1);
    bool last = (it == NIT - 1);
    int t1k = (2 * it + 1) * 64;
    int t2k = (2 * it + 2) * 64;
    int t3k = (2 * it + 3) * 64;
    sx8 fa[8], fb[2];

    PHASE(0, 0, 0, true,
          { stage_half(Bb, K, LDSUB(1, 1, 1), tid, t1k + 32); }, {});
    PHASE(0, 0, 1, false,
          { if (st) stage_half(Ab, K, LDSUB(0, 0, 0), tid, t2k); }, {});
    PHASE(0, 1, 0, true,
          { if (st) stage_half(Bb, K, LDSUB(0, 1, 0), tid, t2k); }, {});
    PHASE(0, 1, 1, false,
          { if (st) stage_half(Ab, K, LDSUB(0, 0, 1), tid, t2k + 32); },
          { if (last) { asm volatile("s_waitcnt vmcnt(0)" ::: "memory"); }
            else      { asm volatile("s_waitcnt vmcnt(6)" ::: "memory"); } });
    PHASE(1, 0, 0, true,
          { if (st) stage_half(Bb, K, LDSUB(0, 1, 1), tid, t2k + 32); }, {});
    PHASE(1, 0, 1, false,
          { if (st) stage_half(Ab, K, LDSUB(1, 0, 0), tid, t3k); }, {});
    PHASE(1, 1, 0, true,
          { if (st) stage_half(Bb, K, LDSUB(1, 1, 0), tid, t3k); }, {});
    // split epilogue: nj 0,1 final after p7 -> store overlapped with p8
    if (last) {
#pragma unroll
      for (int mi = 0; mi < 8; ++mi) {
        *(float4*)(obase + (size_t)mi * 16 * N) =
            (float4){acc[mi][0][0], acc[mi][0][1], acc[mi][0][2], acc[mi][0][3]};
        *(float4*)(obase + (size_t)mi * 16 * N + 16) =
            (float4){acc[mi][1][0], acc[mi][1][1], acc[mi][1][2], acc[mi][1][3]};
      }
    }
    PHASE(1, 1, 1, false,
          { if (st) stage_half(Ab, K, LDSUB(1, 0, 1), tid, t3k + 32); },
          { if (!last) { asm volatile("s_waitcnt vmcnt(6)" ::: "memory"); } });
  }
#undef PHASE

  // remaining quadrants nj 2,3
#pragma unroll
  for (int mi = 0; mi < 8; ++mi) {
    *(float4*)(obase + (size_t)mi * 16 * N + 32) =
        (float4){acc[mi][2][0], acc[mi][2][1], acc[mi][2][2], acc[mi][2][3]};
    *(float4*)(obase + (size_t)mi * 16 * N + 48) =
        (float4){acc[mi][3][0], acc[mi][3][1], acc[mi][3][2], acc[mi][3][3]};
  }
}

// ---------------- flash attention, KVBLK=128, pipelined staging, MFMA row-sum ----------------
__global__ __launch_bounds__(256) void k_attn(const unsigned short* __restrict__ gq,
                                              const unsigned short* __restrict__ gk,
                                              const unsigned short* __restrict__ gvt,
                                              unsigned short* __restrict__ y) {
  __shared__ unsigned short Ks[128 * 64];
  __shared__ unsigned short Vt[64 * 128];
  __shared__ unsigned short Pw[4][16 * 136];
  int id = xcd_swizzle(blockIdx.x, gridDim.x);
  int bh = id >> 4, qt = 15 - (id & 15);
  int tid = threadIdx.x, wid = tid >> 6, lane = tid & 63;
  int lr = lane & 15, lg = lane >> 4;
  int q0 = qt * 64 + wid * 16;
  int qg = q0 + lr;

#define STAGE_K(kt0)                                                                  \
  {                                                                                   \
    _Pragma("unroll")                                                                 \
    for (int i = 0; i < 4; ++i) {                                                     \
      int chunk = i * 256 + tid;                                                      \
      int r = chunk >> 3, s = chunk & 7;                                              \
      gload_lds16(&gk[((size_t)bh * T_SEQ + (kt0) + r) * DH + ((s ^ (r & 7)) << 3)],  \
                  &Ks[chunk << 3]);                                                   \
    }                                                                                 \
  }
#define STAGE_V(kt0)                                                                  \
  {                                                                                   \
    _Pragma("unroll")                                                                 \
    for (int i = 0; i < 4; ++i) {                                                     \
      int chunk = i * 256 + tid;                                                      \
      int r = chunk >> 4, s = chunk & 15;                                             \
      gload_lds16(&gvt[((size_t)bh * DH + r) * T_SEQ + (kt0) + ((s ^ (r & 15)) << 3)],\
                  &Vt[chunk << 3]);                                                   \
    }                                                                                 \
  }

  sx8 qf[2];
  {
    const unsigned short* qp = gq + ((size_t)bh * T_SEQ + qg) * DH + lg * 8;
    qf[0] = *(const sx8*)qp;
    qf[1] = *(const sx8*)(qp + 32);
  }
  sx8 ones;   // bf16 1.0 frag for MFMA row-sum
#pragma unroll
  for (int i = 0; i < 8; ++i) ones[i] = (short)0x3F80;

  fx4 yacc[4] = {};
  fx4 sacc = {};                      // running sum(P) per q-row (MFMA ones-trick)
  float mrun = -1e30f;                // lane-local (q-row = lr), log2 domain

  // prologue: K(0) then V(0); wait K only (V drains at first tile's vmcnt(0))
  STAGE_K(0);
  STAGE_V(0);
  asm volatile("s_waitcnt vmcnt(4)" ::: "memory");
  __builtin_amdgcn_sched_barrier(0);
  __builtin_amdgcn_s_barrier();

  int jmax = qt >> 1;
  for (int j = 0; j <= jmax; ++j) {
    int kt0 = j * 128;
    bool more = (j < jmax);

    // S^T = K Q^T (Q pre-scaled at qkv epilogue -> st already in log2 domain)
    fx4 st[8] = {};
#pragma unroll
    for (int kk = 0; kk < 2; ++kk) {
      int slotz = (kk * 4 + lg) ^ (lr & 7);
#pragma unroll
      for (int mi = 0; mi < 8; ++mi) {
        sx8 kb = *(const sx8*)&Ks[(mi * 16 + lr) * 64 + slotz * 8];
        st[mi] = __builtin_amdgcn_mfma_f32_16x16x32_bf16(kb, qf[kk], st[mi], 0, 0, 0);
      }
    }

    float pvv[8][4];
    float pmax = -1e30f;
    if (j < jmax) {   // bulk tiles: no causal mask
#pragma unroll
      for (int mi = 0; mi < 8; ++mi)
#pragma unroll
        for (int rg = 0; rg < 4; ++rg) {
          float val = st[mi][rg];
          pvv[mi][rg] = val;
          pmax = fmaxf(pmax, val);
        }
    } else {          // final tile: causal mask
#pragma unroll
      for (int mi = 0; mi < 8; ++mi)
#pragma unroll
        for (int rg = 0; rg < 4; ++rg) {
          float val = st[mi][rg];
          if ((kt0 + mi * 16 + lg * 4 + rg) > qg) val = -1e30f;
          pvv[mi][rg] = val;
          pmax = fmaxf(pmax, val);
        }
    }
    pmax = fmaxf(pmax, __shfl_xor(pmax, 16));
    pmax = fmaxf(pmax, __shfl_xor(pmax, 32));
    // defer-max (T13): rescale only when max grew > 11.5 (= e^8 in log2 units)
    if (!__all(pmax <= mrun + 11.5f)) {
      float mnew = fmaxf(mrun, pmax);
      float sc = exp2f(mrun - mnew);
#pragma unroll
      for (int rg = 0; rg < 4; ++rg) sacc[rg] *= sc;
#pragma unroll
      for (int dt = 0; dt < 4; ++dt)
#pragma unroll
        for (int rg = 0; rg < 4; ++rg) yacc[dt][rg] *= sc;
      mrun = mnew;
    }
#pragma unroll
    for (int mi = 0; mi < 8; ++mi)
#pragma unroll
      for (int rg = 0; rg < 4; ++rg)
        pvv[mi][rg] = exp2f(pvv[mi][rg] - mrun);

    // P -> per-wave LDS: uint2 (b64) writes, HW cvt_pk
#pragma unroll
    for (int mi = 0; mi < 8; ++mi) {
      uint2 pk2 = {cvt_pk_bf16(pvv[mi][0], pvv[mi][1]),
                   cvt_pk_bf16(pvv[mi][2], pvv[mi][3])};
      *(uint2*)&Pw[wid][lr * 136 + mi * 16 + lg * 4] = pk2;
    }

    // V(j) landed + all waves' Ks reads complete
    asm volatile("s_waitcnt vmcnt(0)" ::: "memory");
    __builtin_amdgcn_sched_barrier(0);
    __builtin_amdgcn_s_barrier();
    __builtin_amdgcn_sched_barrier(0);

    // stage next K into Ks while PV computes (Ks free after barrier above)
    if (more) STAGE_K(kt0 + 128);

    // PV + MFMA row-sum (ones-frag): sacc[rg] accumulates sum_k P for q=lr
#pragma unroll
    for (int kk = 0; kk < 4; ++kk) {
      sx8 pa = *(const sx8*)&Pw[wid][lr * 136 + kk * 32 + lg * 8];
      int slotz = (kk * 4 + lg) ^ lr;
#pragma unroll
      for (int dt = 0; dt < 4; ++dt) {
        sx8 vb = *(const sx8*)&Vt[(dt * 16 + lr) * 128 + slotz * 8];
        yacc[dt] = __builtin_amdgcn_mfma_f32_16x16x32_bf16(vb, pa, yacc[dt], 0, 0, 0);
      }
      sacc = __builtin_amdgcn_mfma_f32_16x16x32_bf16(ones, pa, sacc, 0, 0, 0);
    }

    if (more) {
      // all waves done reading Vt -> stage next V; then confirm K(j+1) landed
      asm volatile("s_waitcnt lgkmcnt(0)" ::: "memory");
      __builtin_amdgcn_sched_barrier(0);
      __builtin_amdgcn_s_barrier();
      __builtin_amdgcn_sched_barrier(0);
      STAGE_V(kt0 + 128);
      asm volatile("s_waitcnt vmcnt(4)" ::: "memory");   // 4 newest (V) stay in flight
      __builtin_amdgcn_sched_barrier(0);
      __builtin_amdgcn_s_barrier();
    }
  }
#undef STAGE_K
#undef STAGE_V

  float inv = 1.0f / sacc[0];
  int tok = (bh >> 4) * T_SEQ + qg;
  int colbase = (bh & 15) * DH;
#pragma unroll
  for (int dt = 0; dt < 4; ++dt) {
    uint2 o;
    o.x = cvt_pk_bf16(yacc[dt][0] * inv, yacc[dt][1] * inv);
    o.y = cvt_pk_bf16(yacc[dt][2] * inv, yacc[dt][3] * inv);
    *(uint2*)&y[(size_t)tok * DM + colbase + dt * 16 + lg * 4] = o;
  }
}

// ---------------- launcher ----------------
extern "C" void kernel_launch(void* const* d_in, const int* in_sizes, int n_in,
                              void* d_out, int out_size, void* d_ws, size_t ws_size,
                              hipStream_t stream) {
  (void)in_sizes; (void)n_in; (void)out_size; (void)ws_size;
  const int*   idx     = (const int*)d_in[0];
  const float* tok_emb = (const float*)d_in[1];
  const float* pos_emb = (const float*)d_in[2];
  const float* ln1_s   = (const float*)d_in[3];
  const float* ln1_b   = (const float*)d_in[4];
  const float* qkv_w   = (const float*)d_in[5];
  const float* qkv_b   = (const float*)d_in[6];
  const float* out_w   = (const float*)d_in[7];
  const float* out_b   = (const float*)d_in[8];
  const float* ln2_s   = (const float*)d_in[9];
  const float* ln2_b   = (const float*)d_in[10];
  const float* mlp_w1  = (const float*)d_in[11];
  const float* mlp_b1  = (const float*)d_in[12];
  const float* mlp_w2  = (const float*)d_in[13];
  const float* mlp_b2  = (const float*)d_in[14];
  const float* lnf_s   = (const float*)d_in[15];
  const float* lnf_b   = (const float*)d_in[16];
  const float* head_w  = (const float*)d_in[17];

  char* p = (char*)d_ws;
  float* x          = (float*)p;          p += (size_t)NTOK * DM * 4;
  unsigned short* h = (unsigned short*)p; p += (size_t)NTOK * DM * 2;
  unsigned short* qkvb = (unsigned short*)p; p += (size_t)3 * NTOK * DM * 2;
  unsigned short* yb = (unsigned short*)p; p += (size_t)NTOK * DM * 2;
  unsigned short* m1 = (unsigned short*)p; p += (size_t)NTOK * DFF * 2;
  unsigned short* wt = (unsigned short*)p;                         // 64 MB (head)
  unsigned short* wtq  = wt;                                       // 3M elems
  unsigned short* wto  = wt + (size_t)3 * 1024 * 1024;             // 1M
  unsigned short* wtm1 = wt + (size_t)4 * 1024 * 1024;             // 4M
  unsigned short* wtm2 = wt + (size_t)8 * 1024 * 1024;             // 4M (24 MB total)
  unsigned short* part = (unsigned short*)(p + 32 * 1024 * 1024);  // bf16 partials

  dim3 blk(256);

  k_embed_ln<<<NTOK, blk, 0, stream>>>(idx, tok_emb, pos_emb, ln1_s, ln1_b, x, h);

  for (int l = 0; l < NL; ++l) {
    k_wtrans4<<<3072, blk, 0, stream>>>(qkv_w + (size_t)l * DM * 3 * DM,
                                        out_w + (size_t)l * DM * DM,
                                        mlp_w1 + (size_t)l * DM * DFF,
                                        mlp_w2 + (size_t)l * DFF * DM,
                                        wtq, wto, wtm1, wtm2);
    k_gemm<0><<<16 * 24, blk, 0, stream>>>(h, wtq, qkv_b + l * 3 * DM,
                                           nullptr, qkvb, nullptr, 3 * DM, DM, 24, 1);
    k_attn<<<512, blk, 0, stream>>>(qkvb, qkvb + (size_t)NTOK * DM,
                                    qkvb + (size_t)2 * NTOK * DM, yb);
    k_gemm<2><<<16 * 8 * 4, blk, 0, stream>>>(yb, wto, out_b + l * DM,
                                              part, nullptr, nullptr, DM, DM, 8, 4);
    k_reduce_ln<<<NTOK, blk, 0, stream>>>(part, x, ln2_s + l * DM, ln2_b + l * DM, h);
    k_gemm<1><<<16 * 32, blk, 0, stream>>>(h, wtm1, mlp_b1 + l * DFF,
                                           nullptr, m1, nullptr, DFF, DM, 32, 1);
    k_gemm<2><<<16 * 8 * 4, blk, 0, stream>>>(m1, wtm2, mlp_b2 + l * DM,
                                              part, nullptr, nullptr, DM, DFF, 8, 4);
    if (l < NL - 1)
      k_reduce_ln<<<NTOK, blk, 0, stream>>>(part, x, ln1_s + (l + 1) * DM, ln1_b + (l + 1) * DM, h);
    else
      k_reduce_ln<<<NTOK, blk, 0, stream>>>(part, x, lnf_s, lnf_b, h);
  }

  k_wtrans<<<dim3(DM / 64, VOCAB / 64), blk, 0, stream>>>(head_w, wt, DM, VOCAB);
  k_gemm256<<<1000, 512, 0, stream>>>(h, wt, (float*)d_out, VOCAB, DM);
}

// Round 14
// 1083.644 us; speedup vs baseline: 1.2007x; 1.0035x over previous
//
#include <hip/hip_runtime.h>

// GPT2-like forward, MI355X. Round 12:
// - softmax diet: (1) QK scale folded into Q at qkv epilogue, (2) P row-sum via
//   MFMA ones-trick (replaces 32 fadd + 2 shfl), (3) uint2 P-writes (8 ds_write_b64)
// - everything else identical to R11 (head 8-phase, 2-phase layer GEMMs, pipelined attn staging)

#define T_SEQ 1024
#define NTOK  2048   // B*T
#define DM    1024
#define DFF   4096
#define NH    16
#define DH    64
#define NL    6
#define VOCAB 32000

typedef short sx8 __attribute__((ext_vector_type(8)));          // 8 bf16 (4 VGPR) MFMA frag
typedef float fx4 __attribute__((ext_vector_type(4)));          // MFMA acc
typedef unsigned short usx4 __attribute__((ext_vector_type(4)));
typedef unsigned int   uix4 __attribute__((ext_vector_type(4))); // 16B copy

__device__ __forceinline__ unsigned short f2bf(float f) {
  union { float f; unsigned u; } c; c.f = f;
  unsigned r = c.u + 0x7FFFu + ((c.u >> 16) & 1u);   // round-nearest-even
  return (unsigned short)(r >> 16);
}
__device__ __forceinline__ float bf2f(unsigned short u) {
  union { unsigned u; float f; } c; c.u = ((unsigned)u) << 16;
  return c.f;
}
// HW packed f32->2xbf16 convert (no builtin on gfx950; T12 primitive)
__device__ __forceinline__ unsigned cvt_pk_bf16(float lo, float hi) {
  unsigned r;
  asm("v_cvt_pk_bf16_f32 %0, %1, %2" : "=v"(r) : "v"(lo), "v"(hi));
  return r;
}

__device__ __forceinline__ void gload_lds16(const unsigned short* g, unsigned short* l) {
  __builtin_amdgcn_global_load_lds(
      (const __attribute__((address_space(1))) unsigned int*)g,
      (__attribute__((address_space(3))) unsigned int*)l, 16, 0, 0);
}

// bijective XCD-chunked swizzle (m204)
__device__ __forceinline__ int xcd_swizzle(int orig, int nwg) {
  int q = nwg >> 3, r = nwg & 7;
  int xcd = orig & 7, idx = orig >> 3;
  int base = (xcd < r) ? xcd * (q + 1) : r * (q + 1) + (xcd - r) * q;
  return base + idx;
}

// ---------------- fused embedding + ln1(layer0) ----------------
__global__ __launch_bounds__(256) void k_embed_ln(const int* __restrict__ idx,
                                                  const float* __restrict__ tok,
                                                  const float* __restrict__ pos,
                                                  const float* __restrict__ g,
                                                  const float* __restrict__ b,
                                                  float* __restrict__ x,
                                                  unsigned short* __restrict__ h) {
  int token = blockIdx.x;
  int t = token & (T_SEQ - 1);
  int id = idx[token];
  int tid = threadIdx.x;
  int c = tid * 4;
  float4 tv = *(const float4*)&tok[(size_t)id * DM + c];
  float4 pv = *(const float4*)&pos[(size_t)t * DM + c];
  float4 v;
  v.x = tv.x + pv.x; v.y = tv.y + pv.y; v.z = tv.z + pv.z; v.w = tv.w + pv.w;
  *(float4*)&x[(size_t)token * DM + c] = v;
  float s = v.x + v.y + v.z + v.w;
  float q = v.x * v.x + v.y * v.y + v.z * v.z + v.w * v.w;
  for (int off = 32; off > 0; off >>= 1) {
    s += __shfl_down(s, off);
    q += __shfl_down(q, off);
  }
  __shared__ float red[8];
  int wid = tid >> 6, lane = tid & 63;
  if (lane == 0) { red[wid] = s; red[4 + wid] = q; }
  __syncthreads();
  s = red[0] + red[1] + red[2] + red[3];
  q = red[4] + red[5] + red[6] + red[7];
  float mu = s * (1.0f / DM);
  float var = q * (1.0f / DM) - mu * mu;
  float rstd = rsqrtf(var + 1e-5f);
  float4 gg = *(const float4*)&g[c];
  float4 bb = *(const float4*)&b[c];
  uint2 o;
  o.x = cvt_pk_bf16((v.x - mu) * rstd * gg.x + bb.x, (v.y - mu) * rstd * gg.y + bb.y);
  o.y = cvt_pk_bf16((v.z - mu) * rstd * gg.z + bb.z, (v.w - mu) * rstd * gg.w + bb.w);
  *(uint2*)&h[(size_t)token * DM + c] = o;
}

// ------------- fused split-K(4) reduce (bf16 partials) + residual + layernorm -------------
__global__ __launch_bounds__(256) void k_reduce_ln(const unsigned short* __restrict__ part,
                                                   float* __restrict__ x,
                                                   const float* __restrict__ g,
                                                   const float* __restrict__ b,
                                                   unsigned short* __restrict__ h) {
  int row = blockIdx.x;
  int tid = threadIdx.x;
  int c = tid * 4;
  float4 v = *(const float4*)&x[(size_t)row * DM + c];
#pragma unroll
  for (int s4 = 0; s4 < 4; ++s4) {
    usx4 p = *(const usx4*)&part[((size_t)s4 * NTOK + row) * DM + c];
    v.x += bf2f(p[0]); v.y += bf2f(p[1]); v.z += bf2f(p[2]); v.w += bf2f(p[3]);
  }
  *(float4*)&x[(size_t)row * DM + c] = v;
  float s = v.x + v.y + v.z + v.w;
  float q = v.x * v.x + v.y * v.y + v.z * v.z + v.w * v.w;
  for (int off = 32; off > 0; off >>= 1) {
    s += __shfl_down(s, off);
    q += __shfl_down(q, off);
  }
  __shared__ float red[8];
  int wid = tid >> 6, lane = tid & 63;
  if (lane == 0) { red[wid] = s; red[4 + wid] = q; }
  __syncthreads();
  s = red[0] + red[1] + red[2] + red[3];
  q = red[4] + red[5] + red[6] + red[7];
  float mu = s * (1.0f / DM);
  float var = q * (1.0f / DM) - mu * mu;
  float rstd = rsqrtf(var + 1e-5f);
  float4 gg = *(const float4*)&g[c];
  float4 bb = *(const float4*)&b[c];
  uint2 o;
  o.x = cvt_pk_bf16((v.x - mu) * rstd * gg.x + bb.x, (v.y - mu) * rstd * gg.y + bb.y);
  o.y = cvt_pk_bf16((v.z - mu) * rstd * gg.z + bb.z, (v.w - mu) * rstd * gg.w + bb.w);
  *(uint2*)&h[(size_t)row * DM + c] = o;
}

// ---------------- weight convert+transpose core ----------------
__device__ __forceinline__ void wtrans_body(const float* __restrict__ W,
                                            unsigned short* __restrict__ WT,
                                            int K, int N, int k0, int n0, int tid) {
  __shared__ float t[64][68];
#pragma unroll
  for (int i = 0; i < 4; ++i) {
    int chunk = i * 256 + tid;
    int r = chunk >> 4, c = (chunk & 15) << 2;
    float4 v = *(const float4*)&W[(size_t)(k0 + r) * N + n0 + c];
    t[r][c] = v.x; t[r][c + 1] = v.y; t[r][c + 2] = v.z; t[r][c + 3] = v.w;
  }
  __syncthreads();
#pragma unroll
  for (int i = 0; i < 4; ++i) {
    int chunk = i * 256 + tid;
    int n = chunk >> 4, c = (chunk & 15) << 2;
    uint2 o;
    o.x = cvt_pk_bf16(t[c][n], t[c + 1][n]);
    o.y = cvt_pk_bf16(t[c + 2][n], t[c + 3][n]);
    *(uint2*)&WT[(size_t)(n0 + n) * K + k0 + c] = o;
  }
}

// standalone (head)
__global__ __launch_bounds__(256) void k_wtrans(const float* __restrict__ W,
                                                unsigned short* __restrict__ WT,
                                                int K, int N) {
  wtrans_body(W, WT, K, N, blockIdx.x * 64, blockIdx.y * 64, threadIdx.x);
}

// all 4 per-layer weights in one launch (segmented block ranges)
__global__ __launch_bounds__(256) void k_wtrans4(const float* __restrict__ W0,
                                                 const float* __restrict__ W1,
                                                 const float* __restrict__ W2,
                                                 const float* __restrict__ W3,
                                                 unsigned short* __restrict__ T0,
                                                 unsigned short* __restrict__ T1,
                                                 unsigned short* __restrict__ T2,
                                                 unsigned short* __restrict__ T3) {
  int id = blockIdx.x;
  const float* W; unsigned short* WT; int K, N, lid;
  if (id < 768)       { W = W0; WT = T0; K = 1024; N = 3072; lid = id; }
  else if (id < 1024) { W = W1; WT = T1; K = 1024; N = 1024; lid = id - 768; }
  else if (id < 2048) { W = W2; WT = T2; K = 1024; N = 4096; lid = id - 1024; }
  else                { W = W3; WT = T3; K = 4096; N = 1024; lid = id - 2048; }
  int kb = K >> 6;
  wtrans_body(W, WT, K, N, (lid % kb) * 64, (lid / kb) * 64, threadIdx.x);
}

// ---------------- 128x128 GEMM, T3 2-phase prefetch ----------------
// EPI: 0=qkv scatter(+bias, Q pre-scaled by SCL, V transposed), 1=gelu->bf16, 2=bf16 partials
template <int EPI>
__global__ __launch_bounds__(256) void k_gemm(const unsigned short* __restrict__ A,
                                              const unsigned short* __restrict__ BT,
                                              const float* __restrict__ bias,
                                              unsigned short* __restrict__ part,
                                              unsigned short* __restrict__ outb,
                                              float* __restrict__ outf,
                                              int N, int K, int NT, int KS) {
  __shared__ unsigned short As[2][128 * 64];
  __shared__ unsigned short Bs[2][128 * 64];
  int tid = threadIdx.x;
  int wid = tid >> 6, lane = tid & 63;
  int lr = lane & 15, lg = lane >> 4;

  int id = xcd_swizzle(blockIdx.x, gridDim.x);
  int mt = id & 15;
  int rest = id >> 4;
  int nt = rest % NT;
  int ks = rest / NT;
  int m0 = mt * 128, n0 = nt * 128;
  int Kslice = K / KS;
  int kbeg = ks * Kslice;
  int nk = Kslice >> 6;

  int wm = (wid >> 1) * 64, wn = (wid & 1) * 64;

  fx4 acc[4][4] = {};

#define GSTAGE(buf, kt)                                                         \
  {                                                                             \
    _Pragma("unroll")                                                           \
    for (int i = 0; i < 4; ++i) {                                               \
      int chunk = i * 256 + tid;                                                \
      int r = chunk >> 3, slot = chunk & 7;                                     \
      int c = ((slot ^ (r & 7)) << 3);                                          \
      gload_lds16(&A[(size_t)(m0 + r) * K + (kt) + c], &As[buf][chunk << 3]);   \
      gload_lds16(&BT[(size_t)(n0 + r) * K + (kt) + c], &Bs[buf][chunk << 3]);  \
    }                                                                           \
  }

  GSTAGE(0, kbeg);
  for (int ik = 0; ik < nk; ++ik) {
    int cur = ik & 1;
    if (ik + 1 < nk) {
      GSTAGE(cur ^ 1, kbeg + (ik + 1) * 64);
      asm volatile("s_waitcnt vmcnt(8)" ::: "memory");   // oldest 8 = current tile
    } else {
      asm volatile("s_waitcnt vmcnt(0)" ::: "memory");
    }
    __builtin_amdgcn_sched_barrier(0);
    __builtin_amdgcn_s_barrier();                        // current tile visible to all
    __builtin_amdgcn_sched_barrier(0);
#pragma unroll
    for (int kk = 0; kk < 2; ++kk) {
      int slotz = (kk * 4 + lg) ^ (lr & 7);
      sx8 fa[4], fb[4];
#pragma unroll
      for (int mi = 0; mi < 4; ++mi)
        fa[mi] = *(const sx8*)&As[cur][(wm + mi * 16 + lr) * 64 + slotz * 8];
#pragma unroll
      for (int ni = 0; ni < 4; ++ni)
        fb[ni] = *(const sx8*)&Bs[cur][(wn + ni * 16 + lr) * 64 + slotz * 8];
#pragma unroll
      for (int mi = 0; mi < 4; ++mi)
#pragma unroll
        for (int ni = 0; ni < 4; ++ni)
          acc[mi][ni] = __builtin_amdgcn_mfma_f32_16x16x32_bf16(fb[ni], fa[mi], acc[mi][ni], 0, 0, 0);
    }
    asm volatile("s_waitcnt lgkmcnt(0)" ::: "memory");   // my ds_reads landed
    __builtin_amdgcn_sched_barrier(0);
    __builtin_amdgcn_s_barrier();                        // safe to overwrite cur next iter
  }
#undef GSTAGE

#pragma unroll
  for (int ni = 0; ni < 4; ++ni) {
    int col0 = n0 + wn + ni * 16 + lg * 4;
    float4 bv = {0.f, 0.f, 0.f, 0.f};
    if (bias && ks == 0) bv = *(const float4*)&bias[col0];
#pragma unroll
    for (int mi = 0; mi < 4; ++mi) {
      int row = m0 + wm + mi * 16 + lr;
      float v0 = acc[mi][ni][0] + bv.x;
      float v1 = acc[mi][ni][1] + bv.y;
      float v2 = acc[mi][ni][2] + bv.z;
      float v3 = acc[mi][ni][3] + bv.w;
      if constexpr (EPI == 0) {
        int bb = row >> 10, tt = row & 1023;
        if (col0 < 2048) {
          int which = col0 >> 10;
          if (which == 0) {  // pre-scale Q by 1/sqrt(d)*log2(e): (Q*s)@K == (Q@K)*s
            const float SCLQ = 0.125f * 1.44269504f;
            v0 *= SCLQ; v1 *= SCLQ; v2 *= SCLQ; v3 *= SCLQ;
          }
          int hc = col0 & 1023;
          uint2 o = {cvt_pk_bf16(v0, v1), cvt_pk_bf16(v2, v3)};
          *(uint2*)&outb[(size_t)which * NTOK * DM +
                         (((size_t)bb * NH + (hc >> 6)) * T_SEQ + tt) * DH + (hc & 63)] = o;
        } else {
          int dc = col0 - 2048;
          unsigned short* vt = outb + (size_t)2 * NTOK * DM;
          size_t base = (((size_t)bb * NH + (dc >> 6)) * DH + (dc & 63)) * T_SEQ + tt;
          vt[base] = f2bf(v0);
          vt[base + T_SEQ] = f2bf(v1);
          vt[base + 2 * T_SEQ] = f2bf(v2);
          vt[base + 3 * T_SEQ] = f2bf(v3);
        }
      } else if constexpr (EPI == 1) {
        float g0 = 0.5f * v0 * (1.0f + erff(v0 * 0.70710678f));
        float g1 = 0.5f * v1 * (1.0f + erff(v1 * 0.70710678f));
        float g2 = 0.5f * v2 * (1.0f + erff(v2 * 0.70710678f));
        float g3 = 0.5f * v3 * (1.0f + erff(v3 * 0.70710678f));
        uint2 o = {cvt_pk_bf16(g0, g1), cvt_pk_bf16(g2, g3)};
        *(uint2*)&outb[(size_t)row * N + col0] = o;
      } else {  // bf16 partial slice (split-K)
        uint2 o = {cvt_pk_bf16(v0, v1), cvt_pk_bf16(v2, v3)};
        *(uint2*)&part[((size_t)ks * NTOK + row) * DM + col0] = o;
      }
    }
  }
}

// ---------------- 256x256 8-phase GEMM (head) — R8 proven version ----------------
#define LDSUB(buf, ab, kk) (lds + (((buf) * 2 + (ab)) * 2 + (kk)) * 8192)

__device__ __forceinline__ void stage_half(const unsigned short* g, int rowstride,
                                           unsigned short* ldsbase, int tid, int k0) {
#pragma unroll
  for (int r = 0; r < 2; ++r) {
    int chunk = r * 512 + tid;
    int row = chunk >> 2, slot = chunk & 3;
    gload_lds16(g + (size_t)row * rowstride + k0 + ((slot ^ ((row >> 1) & 3)) << 3),
                ldsbase + (chunk << 3));
  }
}

__global__ __launch_bounds__(512, 2) void k_gemm256(const unsigned short* __restrict__ A,
                                                    const unsigned short* __restrict__ BT,
                                                    float* __restrict__ outf,
                                                    int N, int K) {
  __shared__ unsigned short lds[8 * 8192];   // 128 KB
  int tid = threadIdx.x;
  int wid = tid >> 6, lane = tid & 63;
  int lr = lane & 15, lg = lane >> 4;
  int wm2 = wid >> 2, wn4 = wid & 3;
  int id = xcd_swizzle(blockIdx.x, gridDim.x);
  int mt = id & 7, nt = id >> 3;          // mt fastest: 8 blocks share B panel
  int m0 = mt * 256, n0 = nt * 256;
  const unsigned short* Ab = A + (size_t)m0 * K;
  const unsigned short* Bb = BT + (size_t)n0 * K;
  int NIT = K >> 7;                        // 2 K-tiles (of 64) per iteration
  int swz = (lg ^ ((lr >> 1) & 3)) << 3;   // matches stage_half swizzle
  float* obase = outf + (size_t)(m0 + wm2 * 128 + lr) * N + n0 + wn4 * 64 + lg * 4;

  fx4 acc[8][4] = {};

  // prologue: tile0 {A0,B0,A1,B1}, tile1 {A0,B0,A1} = 7 half-tiles (14 loads)
  stage_half(Ab, K, LDSUB(0, 0, 0), tid, 0);
  stage_half(Bb, K, LDSUB(0, 1, 0), tid, 0);
  stage_half(Ab, K, LDSUB(0, 0, 1), tid, 32);
  stage_half(Bb, K, LDSUB(0, 1, 1), tid, 32);
  stage_half(Ab, K, LDSUB(1, 0, 0), tid, 64);
  stage_half(Bb, K, LDSUB(1, 1, 0), tid, 64);
  stage_half(Ab, K, LDSUB(1, 0, 1), tid, 96);
  asm volatile("s_waitcnt vmcnt(6)" ::: "memory");   // tile0 fully staged
  __builtin_amdgcn_s_barrier();

#define PHASE(BUF, KK, NHH, LOADA, STG, VMW)                                         \
  {                                                                                  \
    if (LOADA) {                                                                     \
      const unsigned short* sA = LDSUB(BUF, 0, KK);                                  \
      _Pragma("unroll")                                                              \
      for (int mi = 0; mi < 8; ++mi)                                                 \
        fa[mi] = *(const sx8*)&sA[(wm2 * 128 + mi * 16 + lr) * 32 + swz];            \
    }                                                                                \
    {                                                                                \
      const unsigned short* sB = LDSUB(BUF, 1, KK);                                  \
      _Pragma("unroll")                                                              \
      for (int j = 0; j < 2; ++j)                                                    \
        fb[j] = *(const sx8*)&sB[(wn4 * 64 + (NHH) * 32 + j * 16 + lr) * 32 + swz];  \
    }                                                                                \
    STG;                                                                             \
    VMW;                                                                             \
    __builtin_amdgcn_sched_barrier(0);                                               \
    __builtin_amdgcn_s_barrier();                                                    \
    asm volatile("s_waitcnt lgkmcnt(0)" ::: "memory");                               \
    __builtin_amdgcn_sched_barrier(0);                                               \
    __builtin_amdgcn_s_setprio(1);                                                   \
    _Pragma("unroll")                                                                \
    for (int mi = 0; mi < 8; ++mi) {                                                 \
      acc[mi][(NHH) * 2 + 0] = __builtin_amdgcn_mfma_f32_16x16x32_bf16(              \
          fb[0], fa[mi], acc[mi][(NHH) * 2 + 0], 0, 0, 0);                           \
      acc[mi][(NHH) * 2 + 1] = __builtin_amdgcn_mfma_f32_16x16x32_bf16(              \
          fb[1], fa[mi], acc[mi][(NHH) * 2 + 1], 0, 0, 0);                           \
    }                                                                                \
    __builtin_amdgcn_s_setprio(0);                                                   \
    __builtin_amdgcn_sched_barrier(0);                                               \
    __builtin_amdgcn_s_barrier();                                                    \
  }

  for (int it = 0; it < NIT; ++it) {
    bool st = (it < NIT - 1);
    bool last = (it == NIT - 1);
    int t1k = (2 * it + 1) * 64;
    int t2k = (2 * it + 2) * 64;
    int t3k = (2 * it + 3) * 64;
    sx8 fa[8], fb[2];

    PHASE(0, 0, 0, true,
          { stage_half(Bb, K, LDSUB(1, 1, 1), tid, t1k + 32); }, {});
    PHASE(0, 0, 1, false,
          { if (st) stage_half(Ab, K, LDSUB(0, 0, 0), tid, t2k); }, {});
    PHASE(0, 1, 0, true,
          { if (st) stage_half(Bb, K, LDSUB(0, 1, 0), tid, t2k); }, {});
    PHASE(0, 1, 1, false,
          { if (st) stage_half(Ab, K, LDSUB(0, 0, 1), tid, t2k + 32); },
          { if (last) { asm volatile("s_waitcnt vmcnt(0)" ::: "memory"); }
            else      { asm volatile("s_waitcnt vmcnt(6)" ::: "memory"); } });
    PHASE(1, 0, 0, true,
          { if (st) stage_half(Bb, K, LDSUB(0, 1, 1), tid, t2k + 32); }, {});
    PHASE(1, 0, 1, false,
          { if (st) stage_half(Ab, K, LDSUB(1, 0, 0), tid, t3k); }, {});
    PHASE(1, 1, 0, true,
          { if (st) stage_half(Bb, K, LDSUB(1, 1, 0), tid, t3k); }, {});
    // split epilogue: nj 0,1 final after p7 -> store overlapped with p8
    if (last) {
#pragma unroll
      for (int mi = 0; mi < 8; ++mi) {
        *(float4*)(obase + (size_t)mi * 16 * N) =
            (float4){acc[mi][0][0], acc[mi][0][1], acc[mi][0][2], acc[mi][0][3]};
        *(float4*)(obase + (size_t)mi * 16 * N + 16) =
            (float4){acc[mi][1][0], acc[mi][1][1], acc[mi][1][2], acc[mi][1][3]};
      }
    }
    PHASE(1, 1, 1, false,
          { if (st) stage_half(Ab, K, LDSUB(1, 0, 1), tid, t3k + 32); },
          { if (!last) { asm volatile("s_waitcnt vmcnt(6)" ::: "memory"); } });
  }
#undef PHASE

  // remaining quadrants nj 2,3
#pragma unroll
  for (int mi = 0; mi < 8; ++mi) {
    *(float4*)(obase + (size_t)mi * 16 * N + 32) =
        (float4){acc[mi][2][0], acc[mi][2][1], acc[mi][2][2], acc[mi][2][3]};
    *(float4*)(obase + (size_t)mi * 16 * N + 48) =
        (float4){acc[mi][3][0], acc[mi][3][1], acc[mi][3][2], acc[mi][3][3]};
  }
}

// ---------------- flash attention, KVBLK=128, pipelined staging, MFMA row-sum ----------------
__global__ __launch_bounds__(256) void k_attn(const unsigned short* __restrict__ gq,
                                              const unsigned short* __restrict__ gk,
                                              const unsigned short* __restrict__ gvt,
                                              unsigned short* __restrict__ y) {
  __shared__ unsigned short Ks[128 * 64];
  __shared__ unsigned short Vt[64 * 128];
  __shared__ unsigned short Pw[4][16 * 136];
  int id = xcd_swizzle(blockIdx.x, gridDim.x);
  int bh = id >> 4, qt = 15 - (id & 15);
  int tid = threadIdx.x, wid = tid >> 6, lane = tid & 63;
  int lr = lane & 15, lg = lane >> 4;
  int q0 = qt * 64 + wid * 16;
  int qg = q0 + lr;

#define STAGE_K(kt0)                                                                  \
  {                                                                                   \
    _Pragma("unroll")                                                                 \
    for (int i = 0; i < 4; ++i) {                                                     \
      int chunk = i * 256 + tid;                                                      \
      int r = chunk >> 3, s = chunk & 7;                                              \
      gload_lds16(&gk[((size_t)bh * T_SEQ + (kt0) + r) * DH + ((s ^ (r & 7)) << 3)],  \
                  &Ks[chunk << 3]);                                                   \
    }                                                                                 \
  }
#define STAGE_V(kt0)                                                                  \
  {                                                                                   \
    _Pragma("unroll")                                                                 \
    for (int i = 0; i < 4; ++i) {                                                     \
      int chunk = i * 256 + tid;                                                      \
      int r = chunk >> 4, s = chunk & 15;                                             \
      gload_lds16(&gvt[((size_t)bh * DH + r) * T_SEQ + (kt0) + ((s ^ (r & 15)) << 3)],\
                  &Vt[chunk << 3]);                                                   \
    }                                                                                 \
  }

  sx8 qf[2];
  {
    const unsigned short* qp = gq + ((size_t)bh * T_SEQ + qg) * DH + lg * 8;
    qf[0] = *(const sx8*)qp;
    qf[1] = *(const sx8*)(qp + 32);
  }
  sx8 ones;   // bf16 1.0 frag for MFMA row-sum
#pragma unroll
  for (int i = 0; i < 8; ++i) ones[i] = (short)0x3F80;

  fx4 yacc[4] = {};
  fx4 sacc = {};                      // running sum(P) per q-row (MFMA ones-trick)
  float mrun = -1e30f;                // lane-local (q-row = lr), log2 domain

  // prologue: K(0) then V(0); wait K only (V drains at first tile's vmcnt(0))
  STAGE_K(0);
  STAGE_V(0);
  asm volatile("s_waitcnt vmcnt(4)" ::: "memory");
  __builtin_amdgcn_sched_barrier(0);
  __builtin_amdgcn_s_barrier();

  int jmax = qt >> 1;
  for (int j = 0; j <= jmax; ++j) {
    int kt0 = j * 128;
    bool more = (j < jmax);

    // S^T = K Q^T (Q pre-scaled at qkv epilogue -> st already in log2 domain)
    fx4 st[8] = {};
#pragma unroll
    for (int kk = 0; kk < 2; ++kk) {
      int slotz = (kk * 4 + lg) ^ (lr & 7);
#pragma unroll
      for (int mi = 0; mi < 8; ++mi) {
        sx8 kb = *(const sx8*)&Ks[(mi * 16 + lr) * 64 + slotz * 8];
        st[mi] = __builtin_amdgcn_mfma_f32_16x16x32_bf16(kb, qf[kk], st[mi], 0, 0, 0);
      }
    }

    float pvv[8][4];
    float pmax = -1e30f;
    if (j < jmax) {   // bulk tiles: no causal mask
#pragma unroll
      for (int mi = 0; mi < 8; ++mi)
#pragma unroll
        for (int rg = 0; rg < 4; ++rg) {
          float val = st[mi][rg];
          pvv[mi][rg] = val;
          pmax = fmaxf(pmax, val);
        }
    } else {          // final tile: causal mask
#pragma unroll
      for (int mi = 0; mi < 8; ++mi)
#pragma unroll
        for (int rg = 0; rg < 4; ++rg) {
          float val = st[mi][rg];
          if ((kt0 + mi * 16 + lg * 4 + rg) > qg) val = -1e30f;
          pvv[mi][rg] = val;
          pmax = fmaxf(pmax, val);
        }
    }
    pmax = fmaxf(pmax, __shfl_xor(pmax, 16));
    pmax = fmaxf(pmax, __shfl_xor(pmax, 32));
    // defer-max (T13): rescale only when max grew > 11.5 (= e^8 in log2 units)
    if (!__all(pmax <= mrun + 11.5f)) {
      float mnew = fmaxf(mrun, pmax);
      float sc = exp2f(mrun - mnew);
#pragma unroll
      for (int rg = 0; rg < 4; ++rg) sacc[rg] *= sc;
#pragma unroll
      for (int dt = 0; dt < 4; ++dt)
#pragma unroll
        for (int rg = 0; rg < 4; ++rg) yacc[dt][rg] *= sc;
      mrun = mnew;
    }
#pragma unroll
    for (int mi = 0; mi < 8; ++mi)
#pragma unroll
      for (int rg = 0; rg < 4; ++rg)
        pvv[mi][rg] = exp2f(pvv[mi][rg] - mrun);

    // P -> per-wave LDS: uint2 (b64) writes, HW cvt_pk
#pragma unroll
    for (int mi = 0; mi < 8; ++mi) {
      uint2 pk2 = {cvt_pk_bf16(pvv[mi][0], pvv[mi][1]),
                   cvt_pk_bf16(pvv[mi][2], pvv[mi][3])};
      *(uint2*)&Pw[wid][lr * 136 + mi * 16 + lg * 4] = pk2;
    }

    // V(j) landed + all waves' Ks reads complete
    asm volatile("s_waitcnt vmcnt(0)" ::: "memory");
    __builtin_amdgcn_sched_barrier(0);
    __builtin_amdgcn_s_barrier();
    __builtin_amdgcn_sched_barrier(0);

    // stage next K into Ks while PV computes (Ks free after barrier above)
    if (more) STAGE_K(kt0 + 128);

    // PV + MFMA row-sum (ones-frag): sacc[rg] accumulates sum_k P for q=lr
#pragma unroll
    for (int kk = 0; kk < 4; ++kk) {
      sx8 pa = *(const sx8*)&Pw[wid][lr * 136 + kk * 32 + lg * 8];
      int slotz = (kk * 4 + lg) ^ lr;
#pragma unroll
      for (int dt = 0; dt < 4; ++dt) {
        sx8 vb = *(const sx8*)&Vt[(dt * 16 + lr) * 128 + slotz * 8];
        yacc[dt] = __builtin_amdgcn_mfma_f32_16x16x32_bf16(vb, pa, yacc[dt], 0, 0, 0);
      }
      sacc = __builtin_amdgcn_mfma_f32_16x16x32_bf16(ones, pa, sacc, 0, 0, 0);
    }

    if (more) {
      // all waves done reading Vt -> stage next V; then confirm K(j+1) landed
      asm volatile("s_waitcnt lgkmcnt(0)" ::: "memory");
      __builtin_amdgcn_sched_barrier(0);
      __builtin_amdgcn_s_barrier();
      __builtin_amdgcn_sched_barrier(0);
      STAGE_V(kt0 + 128);
      asm volatile("s_waitcnt vmcnt(4)" ::: "memory");   // 4 newest (V) stay in flight
      __builtin_amdgcn_sched_barrier(0);
      __builtin_amdgcn_s_barrier();
    }
  }
#undef STAGE_K
#undef STAGE_V

  float inv = 1.0f / sacc[0];
  int tok = (bh >> 4) * T_SEQ + qg;
  int colbase = (bh & 15) * DH;
#pragma unroll
  for (int dt = 0; dt < 4; ++dt) {
    uint2 o;
    o.x = cvt_pk_bf16(yacc[dt][0] * inv, yacc[dt][1] * inv);
    o.y = cvt_pk_bf16(yacc[dt][2] * inv, yacc[dt][3] * inv);
    *(uint2*)&y[(size_t)tok * DM + colbase + dt * 16 + lg * 4] = o;
  }
}

// ---------------- launcher ----------------
extern "C" void kernel_launch(void* const* d_in, const int* in_sizes, int n_in,
                              void* d_out, int out_size, void* d_ws, size_t ws_size,
                              hipStream_t stream) {
  (void)in_sizes; (void)n_in; (void)out_size; (void)ws_size;
  const int*   idx     = (const int*)d_in[0];
  const float* tok_emb = (const float*)d_in[1];
  const float* pos_emb = (const float*)d_in[2];
  const float* ln1_s   = (const float*)d_in[3];
  const float* ln1_b   = (const float*)d_in[4];
  const float* qkv_w   = (const float*)d_in[5];
  const float* qkv_b   = (const float*)d_in[6];
  const float* out_w   = (const float*)d_in[7];
  const float* out_b   = (const float*)d_in[8];
  const float* ln2_s   = (const float*)d_in[9];
  const float* ln2_b   = (const float*)d_in[10];
  const float* mlp_w1  = (const float*)d_in[11];
  const float* mlp_b1  = (const float*)d_in[12];
  const float* mlp_w2  = (const float*)d_in[13];
  const float* mlp_b2  = (const float*)d_in[14];
  const float* lnf_s   = (const float*)d_in[15];
  const float* lnf_b   = (const float*)d_in[16];
  const float* head_w  = (const float*)d_in[17];

  char* p = (char*)d_ws;
  float* x          = (float*)p;          p += (size_t)NTOK * DM * 4;
  unsigned short* h = (unsigned short*)p; p += (size_t)NTOK * DM * 2;
  unsigned short* qkvb = (unsigned short*)p; p += (size_t)3 * NTOK * DM * 2;
  unsigned short* yb = (unsigned short*)p; p += (size_t)NTOK * DM * 2;
  unsigned short* m1 = (unsigned short*)p; p += (size_t)NTOK * DFF * 2;
  unsigned short* wt = (unsigned short*)p;                         // 64 MB (head)
  unsigned short* wtq  = wt;                                       // 3M elems
  unsigned short* wto  = wt + (size_t)3 * 1024 * 1024;             // 1M
  unsigned short* wtm1 = wt + (size_t)4 * 1024 * 1024;             // 4M
  unsigned short* wtm2 = wt + (size_t)8 * 1024 * 1024;             // 4M (24 MB total)
  unsigned short* part = (unsigned short*)(p + 32 * 1024 * 1024);  // bf16 partials

  dim3 blk(256);

  k_embed_ln<<<NTOK, blk, 0, stream>>>(idx, tok_emb, pos_emb, ln1_s, ln1_b, x, h);

  for (int l = 0; l < NL; ++l) {
    k_wtrans4<<<3072, blk, 0, stream>>>(qkv_w + (size_t)l * DM * 3 * DM,
                                        out_w + (size_t)l * DM * DM,
                                        mlp_w1 + (size_t)l * DM * DFF,
                                        mlp_w2 + (size_t)l * DFF * DM,
                                        wtq, wto, wtm1, wtm2);
    k_gemm<0><<<16 * 24, blk, 0, stream>>>(h, wtq, qkv_b + l * 3 * DM,
                                           nullptr, qkvb, nullptr, 3 * DM, DM, 24, 1);
    k_attn<<<512, blk, 0, stream>>>(qkvb, qkvb + (size_t)NTOK * DM,
                                    qkvb + (size_t)2 * NTOK * DM, yb);
    k_gemm<2><<<16 * 8 * 4, blk, 0, stream>>>(yb, wto, out_b + l * DM,
                                              part, nullptr, nullptr, DM, DM, 8, 4);
    k_reduce_ln<<<NTOK, blk, 0, stream>>>(part, x, ln2_s + l * DM, ln2_b + l * DM, h);
    k_gemm<1><<<16 * 32, blk, 0, stream>>>(h, wtm1, mlp_b1 + l * DFF,
                                           nullptr, m1, nullptr, DFF, DM, 32, 1);
    k_gemm<2><<<16 * 8 * 4, blk, 0, stream>>>(m1, wtm2, mlp_b2 + l * DM,
                                              part, nullptr, nullptr, DM, DFF, 8, 4);
    if (l < NL - 1)
      k_reduce_ln<<<NTOK, blk, 0, stream>>>(part, x, ln1_s + (l + 1) * DM, ln1_b + (l + 1) * DM, h);
    else
      k_reduce_ln<<<NTOK, blk, 0, stream>>>(part, x, lnf_s, lnf_b, h);
  }

  k_wtrans<<<dim3(DM / 64, VOCAB / 64), blk, 0, stream>>>(head_w, wt, DM, VOCAB);
  k_gemm256<<<1000, 512, 0, stream>>>(h, wt, (float*)d_out, VOCAB, DM);
}